// Round 4
// baseline (2445.031 us; speedup 1.0000x reference)
//
#include <hip/hip_runtime.h>
#include <hip/hip_bf16.h>

typedef unsigned short u16;
typedef __attribute__((ext_vector_type(8))) short bf16x8;
typedef __attribute__((ext_vector_type(4))) float f32x4;

#define NB 8
#define NS 1024
#define ND 768
#define NH 12
#define NL 8
#define NDH 64
#define NV 1024
#define NCONDV 256
#define NTOK (NB*NS)

union BF8 { bf16x8 v; u16 u[8]; };
union US4 { ushort4 v; u16 u[4]; };

__device__ __forceinline__ float b2f(u16 u){ return __uint_as_float(((unsigned)u) << 16); }
__device__ __forceinline__ u16 f2b(float f){
  unsigned u = __float_as_uint(f);
  return (u16)((u + 0x7fffu + ((u >> 16) & 1u)) >> 16);   // RNE, finite inputs only
}

__device__ __forceinline__ void glds16(const u16* g, u16* l) {
  __builtin_amdgcn_global_load_lds((const __attribute__((address_space(1))) void*)g,
                                   (__attribute__((address_space(3))) void*)l, 16, 0, 0);
}

#define MEMFENCE asm volatile("" ::: "memory")

// ---------------- embedding + sinusoidal PE -> x fp32 ----------------
__global__ __launch_bounds__(256) void k_embed(const int* __restrict__ tokens,
                                               const float* __restrict__ emb,
                                               float* __restrict__ x)
{
  const int t = blockIdx.x;
  const int s = t & (NS - 1);
  const int tok = tokens[t];
  const float c = (float)(-9.210340371976184 / 768.0);
  for (int d = threadIdx.x; d < ND; d += 256) {
    float div = expf((float)(d & ~1) * c);
    float ang = (float)s * div;
    float pe = (d & 1) ? cosf(ang) : sinf(ang);
    x[(size_t)t*ND + d] = emb[(size_t)tok*ND + d] + pe;
  }
}

// ---------------- action vector ----------------
__global__ __launch_bounds__(256) void k_actvec(const int* __restrict__ actions,
                                                const float* __restrict__ act_emb,
                                                float* __restrict__ a)
{
  const int b = blockIdx.x, j = threadIdx.x;
  const int i = j >> 6, kk = j & 63;
  const int act = actions[b*4 + i];
  a[b*NCONDV + j] = act_emb[(size_t)act*64 + kk];
}

// ---------------- conditional LN gains ----------------
__global__ __launch_bounds__(256) void k_gains(const float* __restrict__ a,
    const float* __restrict__ g1, const float* __restrict__ b1,
    const float* __restrict__ g2, const float* __restrict__ b2,
    const float* __restrict__ gf, const float* __restrict__ bfp,
    float* __restrict__ outp)
{
  __shared__ float sa[NB*NCONDV];
  const int m = blockIdx.x, dc = blockIdx.y;
  for (int i = threadIdx.x; i < NB*NCONDV; i += 256) sa[i] = a[i];
  __syncthreads();
  const float* W;
  if (m < 32) {
    int ll = m >> 2, w = m & 3;
    const float* base = (w==0) ? g1 : (w==1) ? b1 : (w==2) ? g2 : b2;
    W = base + (size_t)ll * NCONDV * ND;
  } else {
    W = (m == 32) ? gf : bfp;
  }
  const int d = dc*256 + threadIdx.x;
  float acc[NB] = {0,0,0,0,0,0,0,0};
  for (int j = 0; j < NCONDV; j++) {
    float w = W[(size_t)j*ND + d];
    #pragma unroll
    for (int bb = 0; bb < NB; bb++) acc[bb] += sa[bb*NCONDV + j] * w;
  }
  #pragma unroll
  for (int bb = 0; bb < NB; bb++) outp[((size_t)m*NB + bb)*ND + d] = acc[bb];
}

// ---------------- conditional layernorm: one wave per token, no barriers ----------------
__global__ __launch_bounds__(256) void k_cln(const float* __restrict__ x,
                                             const float* __restrict__ g,
                                             const float* __restrict__ bb,
                                             u16* __restrict__ h)
{
  const int tid = threadIdx.x, w = tid >> 6, lane = tid & 63;
  const int t = blockIdx.x*4 + w;
  const int bi = t >> 10;
  const float* xr = x + (size_t)t*ND;
  f32x4 v0 = *(const f32x4*)(xr + lane*4);
  f32x4 v1 = *(const f32x4*)(xr + 256 + lane*4);
  f32x4 v2 = *(const f32x4*)(xr + 512 + lane*4);
  float s = (v0[0]+v0[1]+v0[2]+v0[3]) + (v1[0]+v1[1]+v1[2]+v1[3]) + (v2[0]+v2[1]+v2[2]+v2[3]);
  #pragma unroll
  for (int off = 1; off < 64; off <<= 1) s += __shfl_xor(s, off);
  float mu = s * (1.0f/768.0f);
  float s2 = 0.f;
  #pragma unroll
  for (int i = 0; i < 4; i++) { v0[i] -= mu; s2 += v0[i]*v0[i]; }
  #pragma unroll
  for (int i = 0; i < 4; i++) { v1[i] -= mu; s2 += v1[i]*v1[i]; }
  #pragma unroll
  for (int i = 0; i < 4; i++) { v2[i] -= mu; s2 += v2[i]*v2[i]; }
  #pragma unroll
  for (int off = 1; off < 64; off <<= 1) s2 += __shfl_xor(s2, off);
  float rs = rsqrtf(s2 * (1.0f/768.0f) + 1e-5f);
  const float* gr = g + (size_t)bi*ND;
  const float* br = bb + (size_t)bi*ND;
  u16* hr = h + (size_t)t*ND;
  #pragma unroll
  for (int j = 0; j < 3; j++) {
    f32x4 vv = (j==0) ? v0 : (j==1) ? v1 : v2;
    f32x4 gg = *(const f32x4*)(gr + j*256 + lane*4);
    f32x4 bv = *(const f32x4*)(br + j*256 + lane*4);
    US4 o;
    #pragma unroll
    for (int i = 0; i < 4; i++) o.u[i] = f2b(vv[i]*rs*gg[i] + bv[i]);
    *(ushort4*)(hr + j*256 + lane*4) = o.v;
  }
}

// ---------------- weight prep: fp32 [K][N] (xL) -> bf16 [N][K] ----------------
__global__ __launch_bounds__(256) void k_wprep(const float* __restrict__ src,
                                               u16* __restrict__ dst, int K, int N)
{
  __shared__ u16 t[64][65];
  const int k0 = blockIdx.x*64, n0 = blockIdx.y*64;
  const size_t mz = (size_t)blockIdx.z * K * N;
  src += mz; dst += mz;
  {
    int r = threadIdx.x >> 2, c0 = (threadIdx.x & 3) * 16;
    const float* s = src + (size_t)(k0 + r)*N + n0 + c0;
    f32x4 a = *(const f32x4*)s, b = *(const f32x4*)(s+4);
    f32x4 c = *(const f32x4*)(s+8), d = *(const f32x4*)(s+12);
    #pragma unroll
    for (int i = 0; i < 4; i++) {
      t[r][c0+i]    = f2b(a[i]);
      t[r][c0+4+i]  = f2b(b[i]);
      t[r][c0+8+i]  = f2b(c[i]);
      t[r][c0+12+i] = f2b(d[i]);
    }
  }
  __syncthreads();
  {
    int rn = threadIdx.x >> 2, kc = (threadIdx.x & 3)*16;
    u16* dp = dst + (size_t)(n0+rn)*K + k0 + kc;
    BF8 o0, o1;
    #pragma unroll
    for (int i = 0; i < 8; i++) { o0.u[i] = t[kc+i][rn]; o1.u[i] = t[kc+8+i][rn]; }
    *(bf16x8*)dp = o0.v; *(bf16x8*)(dp+8) = o1.v;
  }
}

// ---------------- per-head QKV projection (fp32 weights) ----------------
__global__ __launch_bounds__(256) void k_qkv(const u16* __restrict__ h,
    const float* __restrict__ Wq, const float* __restrict__ Wk, const float* __restrict__ Wv,
    u16* __restrict__ qo, u16* __restrict__ ko, u16* __restrict__ vo)
{
  __shared__ alignas(16) u16 wlds[64][72];
  const int t0 = blockIdx.x * 64, head = blockIdx.y, which = blockIdx.z;
  const float* W = ((which==0) ? Wq : (which==1) ? Wk : Wv) + (size_t)head*NDH*NDH;
  {
    int d = threadIdx.x >> 2, e0 = (threadIdx.x & 3) * 16;
    const float* wr = W + (size_t)d*NDH + e0;
    f32x4 f0 = *(const f32x4*)wr;
    f32x4 f1 = *(const f32x4*)(wr + 4);
    f32x4 f2 = *(const f32x4*)(wr + 8);
    f32x4 f3 = *(const f32x4*)(wr + 12);
    #pragma unroll
    for (int i = 0; i < 4; i++) {
      wlds[e0+i][d]    = f2b(f0[i]);
      wlds[e0+4+i][d]  = f2b(f1[i]);
      wlds[e0+8+i][d]  = f2b(f2[i]);
      wlds[e0+12+i][d] = f2b(f3[i]);
    }
  }
  __syncthreads();
  const int wave = threadIdx.x >> 6, lane = threadIdx.x & 63;
  const int lo16 = lane & 15, quad = lane >> 4;
  const int arow = t0 + wave*16 + lo16;
  const u16* hr = h + (size_t)arow*ND + head*NDH + quad*8;
  bf16x8 a0 = *(const bf16x8*)hr;
  bf16x8 a1 = *(const bf16x8*)(hr + 32);
  f32x4 acc[4] = {{0,0,0,0},{0,0,0,0},{0,0,0,0},{0,0,0,0}};
  #pragma unroll
  for (int n = 0; n < 4; n++) {
    const u16* bp = &wlds[n*16 + lo16][quad*8];
    bf16x8 b0 = *(const bf16x8*)bp;
    bf16x8 b1 = *(const bf16x8*)(bp + 32);
    acc[n] = __builtin_amdgcn_mfma_f32_16x16x32_bf16(a0, b0, acc[n], 0, 0, 0);
    acc[n] = __builtin_amdgcn_mfma_f32_16x16x32_bf16(a1, b1, acc[n], 0, 0, 0);
  }
  #pragma unroll
  for (int n = 0; n < 4; n++) {
    #pragma unroll
    for (int r = 0; r < 4; r++) {
      int t = t0 + wave*16 + quad*4 + r;
      int bb = t >> 10, s = t & (NS-1);
      int e = n*16 + lo16;
      u16 val = f2b(acc[n][r]);
      if (which == 2) {
        int local = s & 127;
        int col = (s & ~127) | (((local & 15) << 3) | (local >> 4));
        vo[(((size_t)bb*NH + head)*NDH + e)*NS + col] = val;
      } else {
        u16* dst = (which == 0) ? qo : ko;
        dst[(((size_t)bb*NH + head)*NS + s)*NDH + e] = val;
      }
    }
  }
}

// ---------------- flash attention: no-max softmax, slot-permuted P/V ----------------
// v3: T14 async-stage (prefetch K/V tile t+1 into regs during compute of t),
//     exp2 prescale on Q (one v_exp_f32 per score), v_cvt_pk_bf16_f32 P-packing.
__global__ __launch_bounds__(256) void k_attn2(const u16* __restrict__ q,
                                               const u16* __restrict__ kk,
                                               const u16* __restrict__ vt,
                                               u16* __restrict__ o)
{
  __shared__ alignas(16) u16 klds[128][72];
  __shared__ alignas(16) u16 vlds[64][136];
  __shared__ alignas(16) u16 plds[4][16][136];
  const int tid = threadIdx.x, w = tid >> 6, lane = tid & 63;
  const int lo16 = lane & 15, quad = lane >> 4;
  const int bh = blockIdx.x;
  const int b = bh / NH, head = bh - b*NH;
  const int q0 = blockIdx.y*64 + w*16;
  const u16* qb = q  + (size_t)bh*NS*NDH;
  const u16* kb = kk + (size_t)bh*NS*NDH;
  const u16* vb = vt + (size_t)bh*NDH*NS;
  BF8 aq0, aq1;
  {
    const u16* qr = qb + (size_t)(q0 + lo16)*NDH + quad*8;
    BF8 r0, r1; r0.v = *(const bf16x8*)qr; r1.v = *(const bf16x8*)(qr + 32);
    const float qs = 0.125f * 1.44269504088896f;   // fold log2(e): scores in log2 domain
    #pragma unroll
    for (int j = 0; j < 8; j++) {
      aq0.u[j] = f2b(b2f(r0.u[j]) * qs);
      aq1.u[j] = f2b(b2f(r1.u[j]) * qs);
    }
  }
  float lsum[4] = {0,0,0,0};
  f32x4 oacc[4] = {{0,0,0,0},{0,0,0,0},{0,0,0,0},{0,0,0,0}};

  // T14: K/V tile prefetch registers (global -> reg early, reg -> LDS late)
  bf16x8 kreg[4], vreg[4];
  #pragma unroll
  for (int i = 0; i < 4; i++) {
    int c = tid + 256*i;
    kreg[i] = *(const bf16x8*)(kb + (size_t)(c>>3)*NDH + (c&7)*8);
    vreg[i] = *(const bf16x8*)(vb + (size_t)(c>>4)*NS + (c&15)*8);
  }

  for (int kt = 0; kt < NS; kt += 128) {
    __syncthreads();                       // all waves done reading previous tile
    #pragma unroll
    for (int i = 0; i < 4; i++) {
      int c = tid + 256*i;
      *(bf16x8*)&klds[c>>3][(c&7)*8] = kreg[i];
      *(bf16x8*)&vlds[c>>4][(c&15)*8] = vreg[i];
    }
    __syncthreads();                       // tile ready
    if (kt + 128 < NS) {                   // issue next tile's global loads now;
      #pragma unroll                       // latency hides under QK^T/softmax/PV
      for (int i = 0; i < 4; i++) {
        int c = tid + 256*i;
        kreg[i] = *(const bf16x8*)(kb + (size_t)(kt + 128 + (c>>3))*NDH + (c&7)*8);
        vreg[i] = *(const bf16x8*)(vb + (size_t)(c>>4)*NS + (kt + 128) + (c&15)*8);
      }
    }
    f32x4 s[8];
    #pragma unroll
    for (int j = 0; j < 8; j++) {
      const u16* kr = &klds[j*16 + lo16][quad*8];
      bf16x8 b0 = *(const bf16x8*)kr;
      bf16x8 b1 = *(const bf16x8*)(kr + 32);
      f32x4 z = {0,0,0,0};
      z = __builtin_amdgcn_mfma_f32_16x16x32_bf16(aq0.v, b0, z, 0, 0, 0);
      s[j] = __builtin_amdgcn_mfma_f32_16x16x32_bf16(aq1.v, b1, z, 0, 0, 0);
    }
    #pragma unroll
    for (int r = 0; r < 4; r++) {
      float p[8];
      #pragma unroll
      for (int j = 0; j < 8; j++) p[j] = exp2f(s[j][r]);
      unsigned pk32[4];
      #pragma unroll
      for (int j = 0; j < 4; j++)
        asm("v_cvt_pk_bf16_f32 %0, %1, %2" : "=v"(pk32[j]) : "v"(p[2*j]), "v"(p[2*j+1]));
      float ps = 0.f;
      #pragma unroll
      for (int j = 0; j < 4; j++) {
        ps += __uint_as_float(pk32[j] << 16);
        ps += __uint_as_float(pk32[j] & 0xffff0000u);
      }
      lsum[r] += ps;
      union { unsigned u[4]; bf16x8 v; } pkv;
      #pragma unroll
      for (int j = 0; j < 4; j++) pkv.u[j] = pk32[j];
      *(bf16x8*)&plds[w][quad*4 + r][lo16*8] = pkv.v;
    }
    #pragma unroll
    for (int kc = 0; kc < 4; kc++) {
      bf16x8 pa = *(const bf16x8*)&plds[w][lo16][kc*32 + quad*8];
      #pragma unroll
      for (int n = 0; n < 4; n++) {
        bf16x8 vf = *(const bf16x8*)&vlds[n*16 + lo16][kc*32 + quad*8];
        oacc[n] = __builtin_amdgcn_mfma_f32_16x16x32_bf16(pa, vf, oacc[n], 0, 0, 0);
      }
    }
  }
  #pragma unroll
  for (int r = 0; r < 4; r++) {
    #pragma unroll
    for (int off = 1; off < 16; off <<= 1) lsum[r] += __shfl_xor(lsum[r], off);
  }
  #pragma unroll
  for (int n = 0; n < 4; n++) {
    #pragma unroll
    for (int r = 0; r < 4; r++) {
      int s_ = q0 + quad*4 + r;
      int d = head*NDH + n*16 + lo16;
      o[((size_t)b*NS + s_)*ND + d] = f2b(oacc[n][r] / lsum[r]);
    }
  }
}

// ================= 256x256 GEMM, double-buffered, 128x64 wave tiles =================
// BM=BN=256, BK=64, 512 thr (8 waves 2m x 4n, each owns 128x64 of C).
// LDS: 2 stages x (A 256x64 + B 256x64) u16 = 128KB (dynamic, opt-in).
// Same proven ring control flow: 2 barriers/tile, counted vmcnt(8) (never 0 in loop),
// depth-1 prefetch (issue->use gap = one full tile of MFMA >> L2 latency).
// T2 swizzle identical to k_gemm3 (linear glds dest + inverse-swizzled source).
// Wave tile 128x64: 64 MFMA per 24 ds_read_b128 (ratio 2.67 vs ring's 2.0) and
// 2x MFMA work per barrier pair -> LDS pipe no longer rate-matches the MFMA pipe.
// EPI 0: f32=A@B+bias ; 1: bf16=gelu(A@B+bias) ; 2: f32=A@B+bias+resid
template<int EPI>
__global__ __launch_bounds__(512) void k_gemm4(
    const u16* __restrict__ A, const u16* __restrict__ Bt,
    const float* __restrict__ bias, const float* __restrict__ resid,
    void* __restrict__ out, int M, int N, int K)
{
  extern __shared__ u16 lds[];                 // 2 * 32768 u16
  const int tid = threadIdx.x;
  const int lane = tid & 63, lo16 = lane & 15, quad = lane >> 4;
  const int w = tid >> 6;
  const int wm = (w >> 2) << 7;                // 0,128
  const int wn = (w & 3) << 6;                 // 0,64,128,192

  // T1 XCD swizzle (grids %8 == 0)
  const int nwg = (int)gridDim.x, flat = (int)blockIdx.x;
  const int swzid = ((nwg & 7) == 0) ? ((flat & 7) * (nwg >> 3) + (flat >> 3)) : flat;
  const int nbn = N >> 8;
  const int mb = swzid / nbn, nb = swzid - mb*nbn;
  const int m0 = mb << 8, n0 = nb << 8;
  const int NT = K >> 6;

  // staging map: thread -> (row sr [+c*64], 16B slot ss); LDS dest tid-linear.
  const int sr = tid >> 3, ss = tid & 7;
  const int sg = ((ss ^ (sr & 7)) << 3);       // inverse-swizzled k-offset (u16)
  const u16* Asrc = A + (size_t)(m0 + sr) * K + sg;
  const u16* Bsrc = Bt + (size_t)(n0 + sr) * K + sg;
  const size_t K64 = (size_t)K << 6;           // 64 rows of u16
  u16* const sd = lds + tid * 8;

  // compute-read swizzled granule offsets (u16) for kk=0/1
  const int sw0 = ((quad ^ (lo16 & 7)) << 3);
  const int sw1 = (((4 + quad) ^ (lo16 & 7)) << 3);
  const int arow = (wm + lo16) << 6;
  const int brow = (wn + lo16) << 6;

  // pre-load bias and force retirement so the loop's vmcnt counting stays exact
  float bv[4];
  #pragma unroll
  for (int nf = 0; nf < 4; nf++) {
    bv[nf] = bias[n0 + wn + nf*16 + lo16];
    asm volatile("" :: "v"(bv[nf]));
  }

  f32x4 acc[8][4];
  #pragma unroll
  for (int i = 0; i < 8; i++)
    #pragma unroll
    for (int j = 0; j < 4; j++) acc[i][j] = (f32x4){0,0,0,0};

  auto STAGE = [&](int t, int bi) {
    u16* dst = sd + bi * 32768;
    const size_t ko = (size_t)t << 6;
    #pragma unroll
    for (int c = 0; c < 4; c++) glds16(Asrc + ko + (size_t)c*K64, dst + c*4096);
    #pragma unroll
    for (int c = 0; c < 4; c++) glds16(Bsrc + ko + (size_t)c*K64, dst + 16384 + c*4096);
  };

  STAGE(0, 0);
  for (int t = 0; t < NT; t++) {
    MEMFENCE; __builtin_amdgcn_s_barrier(); MEMFENCE;   // buf (t+1)&1 free (tile t-1 consumed)
    if (t + 1 < NT) {
      STAGE(t + 1, (t + 1) & 1);
      asm volatile("s_waitcnt vmcnt(8)" ::: "memory");  // tile t's 8 loads landed (mine)
    } else {
      asm volatile("s_waitcnt vmcnt(0)" ::: "memory");
    }
    MEMFENCE; __builtin_amdgcn_s_barrier(); MEMFENCE;   // everyone's tile-t loads landed
    const u16* cb = lds + (t & 1) * 32768;
    bf16x8 bfr[4][2];
    #pragma unroll
    for (int nf = 0; nf < 4; nf++) {
      bfr[nf][0] = *(const bf16x8*)(cb + 16384 + brow + nf*1024 + sw0);
      bfr[nf][1] = *(const bf16x8*)(cb + 16384 + brow + nf*1024 + sw1);
    }
    #pragma unroll
    for (int mh = 0; mh < 2; mh++) {
      bf16x8 af[4][2];
      #pragma unroll
      for (int mf = 0; mf < 4; mf++) {
        af[mf][0] = *(const bf16x8*)(cb + arow + (mh*4+mf)*1024 + sw0);
        af[mf][1] = *(const bf16x8*)(cb + arow + (mh*4+mf)*1024 + sw1);
      }
      __builtin_amdgcn_s_setprio(1);
      #pragma unroll
      for (int kk = 0; kk < 2; kk++)
        #pragma unroll
        for (int mf = 0; mf < 4; mf++)
          #pragma unroll
          for (int nf = 0; nf < 4; nf++)
            acc[mh*4+mf][nf] = __builtin_amdgcn_mfma_f32_16x16x32_bf16(af[mf][kk], bfr[nf][kk], acc[mh*4+mf][nf], 0, 0, 0);
      __builtin_amdgcn_s_setprio(0);
    }
  }

  // ---- epilogue
  #pragma unroll
  for (int fi = 0; fi < 8; fi++) {
    #pragma unroll
    for (int nf = 0; nf < 4; nf++) {
      const int col = n0 + wn + nf*16 + lo16;
      #pragma unroll
      for (int r = 0; r < 4; r++) {
        const int row = m0 + wm + fi*16 + quad*4 + r;
        const size_t idx = (size_t)row * N + col;
        float v = acc[fi][nf][r] + bv[nf];
        if (EPI == 1) {
          float u = 0.7978845608028654f*(v + 0.044715f*v*v*v);
          float e = __expf(2.0f*u);
          float th = (e - 1.0f) / (e + 1.0f);
          ((u16*)out)[idx] = f2b(0.5f*v*(1.0f + th));
        } else if (EPI == 2) {
          ((float*)out)[idx] = v + resid[idx];
        } else {
          ((float*)out)[idx] = v;
        }
      }
    }
  }
}

// ================= 256x128 GEMM, 3-stage LDS ring, 2 K-tiles in flight =================
// BM=256, BN=128, BK=64, 512 thr (8 waves 4m x 2n, 64x64 C each).
// LDS: 3 stages x (A 256x64 + B 128x64) u16 = 144KB (dynamic, opt-in; fallback k_gemm_t).
// EPI 0: f32=A@B+bias ; 1: bf16=gelu(A@B+bias) ; 2: f32=A@B+bias+resid
template<int EPI>
__global__ __launch_bounds__(512) void k_gemm3(
    const u16* __restrict__ A, const u16* __restrict__ Bt,
    const float* __restrict__ bias, const float* __restrict__ resid,
    void* __restrict__ out, int M, int N, int K)
{
  extern __shared__ u16 lds[];                 // 3 * 24576 u16
  const int tid = threadIdx.x;
  const int lane = tid & 63, lo16 = lane & 15, quad = lane >> 4;
  const int w = tid >> 6;
  const int wm = (w & 3) << 6;                 // 0,64,128,192
  const int wn = (w >> 2) << 6;                // 0,64

  // T1 XCD swizzle (all grids here are %8 == 0)
  const int nwg = (int)gridDim.x, flat = (int)blockIdx.x;
  const int swzid = (flat & 7) * (nwg >> 3) + (flat >> 3);
  const int nbn = N >> 7;
  const int mb = swzid / nbn, nb = swzid - mb*nbn;
  const int m0 = mb << 8, n0 = nb << 7;
  const int NT = K >> 6;

  // staging map: thread -> (row sr [+c*64], 16B slot ss); LDS dest tid-linear.
  const int sr = tid >> 3, ss = tid & 7;
  const int sg = ((ss ^ (sr & 7)) << 3);       // inverse-swizzled k-offset (u16)
  const u16* Asrc = A + (size_t)(m0 + sr) * K + sg;
  const u16* Bsrc = Bt + (size_t)(n0 + sr) * K + sg;
  const size_t K64 = (size_t)K << 6;           // 64 rows of u16
  u16* const sd = lds + tid * 8;               // linear: row-major [row][slot]

  // compute-read swizzled granule offsets (u16) for kk=0/1
  const int sw0 = ((quad ^ (lo16 & 7)) << 3);
  const int sw1 = (((4 + quad) ^ (lo16 & 7)) << 3);
  const int arow = (wm + lo16) << 6;
  const int brow = (wn + lo16) << 6;

  f32x4 acc[4][4];
  #pragma unroll
  for (int i = 0; i < 4; i++)
    #pragma unroll
    for (int j = 0; j < 4; j++) acc[i][j] = (f32x4){0,0,0,0};

  auto STAGE = [&](int t, int bi) {
    u16* dst = sd + bi * 24576;
    const size_t ko = (size_t)t << 6;
    #pragma unroll
    for (int c = 0; c < 4; c++) glds16(Asrc + ko + (size_t)c*K64, dst + c*4096);
    #pragma unroll
    for (int c = 0; c < 2; c++) glds16(Bsrc + ko + (size_t)c*K64, dst + 16384 + c*4096);
  };

  // prologue: 2 tiles in flight
  STAGE(0, 0);
  if (NT > 1) STAGE(1, 1);

  int cu = 0;                                   // buffer index of tile t
  for (int t = 0; t < NT; t++) {
    const int st = (cu == 0) ? 2 : cu - 1;      // buffer for tile t+2 (= t-1's, now free)
    MEMFENCE; __builtin_amdgcn_s_barrier(); MEMFENCE;   // all waves done reading tile t-1
    if (t + 2 < NT) {
      STAGE(t + 2, st);
      asm volatile("s_waitcnt vmcnt(12)" ::: "memory"); // my share of tile t landed
    } else if (t + 1 < NT) {
      asm volatile("s_waitcnt vmcnt(6)" ::: "memory");
    } else {
      asm volatile("s_waitcnt vmcnt(0)" ::: "memory");
    }
    MEMFENCE; __builtin_amdgcn_s_barrier(); MEMFENCE;   // everyone's share landed
    const u16* cb = lds + cu * 24576;
    bf16x8 af[4][2], bf[4][2];
    #pragma unroll
    for (int mf = 0; mf < 4; mf++) {
      af[mf][0] = *(const bf16x8*)(cb + arow + mf*1024 + sw0);
      af[mf][1] = *(const bf16x8*)(cb + arow + mf*1024 + sw1);
    }
    #pragma unroll
    for (int nf = 0; nf < 4; nf++) {
      bf[nf][0] = *(const bf16x8*)(cb + 16384 + brow + nf*1024 + sw0);
      bf[nf][1] = *(const bf16x8*)(cb + 16384 + brow + nf*1024 + sw1);
    }
    __builtin_amdgcn_s_setprio(1);
    #pragma unroll
    for (int kk = 0; kk < 2; kk++)
      #pragma unroll
      for (int mf = 0; mf < 4; mf++)
        #pragma unroll
        for (int nf = 0; nf < 4; nf++)
          acc[mf][nf] = __builtin_amdgcn_mfma_f32_16x16x32_bf16(af[mf][kk], bf[nf][kk], acc[mf][nf], 0, 0, 0);
    __builtin_amdgcn_s_setprio(0);
    cu = (cu == 2) ? 0 : cu + 1;
  }

  // ---- epilogue
  #pragma unroll
  for (int mf = 0; mf < 4; mf++) {
    #pragma unroll
    for (int nf = 0; nf < 4; nf++) {
      const int col = n0 + wn + nf*16 + lo16;
      const float bv = bias[col];
      #pragma unroll
      for (int r = 0; r < 4; r++) {
        const int row = m0 + wm + mf*16 + quad*4 + r;
        const size_t idx = (size_t)row * N + col;
        float v = acc[mf][nf][r] + bv;
        if (EPI == 1) {
          float u = 0.7978845608028654f*(v + 0.044715f*v*v*v);
          float e = __expf(2.0f*u);
          float th = (e - 1.0f) / (e + 1.0f);
          ((u16*)out)[idx] = f2b(0.5f*v*(1.0f + th));
        } else if (EPI == 2) {
          ((float*)out)[idx] = v + resid[idx];
        } else {
          ((float*)out)[idx] = v;
        }
      }
    }
  }
}

// ---------------- fast GEMM: MTx128 tile, BK=64 via two 32-k half-buffers ----------------
// (fallback if the dynamic-LDS opt-in is refused)
template<int EPI, int MT>
__global__ __launch_bounds__(256) void k_gemm_t(
    const u16* __restrict__ A, const u16* __restrict__ Bt,
    const float* __restrict__ bias, const float* resid,
    void* out, int M, int N, int K)
{
  constexpr int MI = MT/32;                     // m-frags per wave
  __shared__ alignas(16) u16 alds[2*MT*32];     // [half][m][k32], 64B row stride
  __shared__ alignas(16) u16 blds[2*128*32];    // [half][n][k32]
  const int m0 = blockIdx.x*MT, n0 = blockIdx.y*128;
  const int tid = threadIdx.x;
  const int w = tid >> 6, lane = tid & 63, lo16 = lane & 15, quad = lane >> 4;
  const int wm = (w & 1)*(MT/2), wn = (w >> 1)*64;
  f32x4 acc[MI][4];
  #pragma unroll
  for (int i = 0; i < MI; i++)
    #pragma unroll
    for (int j = 0; j < 4; j++) acc[i][j] = (f32x4){0,0,0,0};
  const int r0 = tid >> 2, c0 = (tid & 3)*8;    // staging: row, k-offset within 32-k half
  const u16* Ap = A  + (size_t)(m0 + r0)*K + c0;
  const u16* Bp = Bt + (size_t)(n0 + r0)*K + c0;
  for (int k0 = 0; k0 < K; k0 += 64) {
    __syncthreads();
    #pragma unroll
    for (int h = 0; h < 2; h++) {
      const int ho = h*32;
      glds16(Ap + k0 + ho, alds + h*(MT*32) + tid*8);
      if (MT == 128) glds16(Ap + (size_t)64*K + k0 + ho, alds + h*(MT*32) + 2048 + tid*8);
      glds16(Bp + k0 + ho, blds + h*4096 + tid*8);
      glds16(Bp + (size_t)64*K + k0 + ho, blds + h*4096 + 2048 + tid*8);
    }
    __syncthreads();
    #pragma unroll
    for (int h = 0; h < 2; h++) {
      const u16* ah = alds + h*(MT*32);
      const u16* bh = blds + h*4096;
      bf16x8 af[MI], bf[4];
      #pragma unroll
      for (int i = 0; i < MI; i++) af[i] = *(const bf16x8*)&ah[(wm + i*16 + lo16)*32 + quad*8];
      #pragma unroll
      for (int j = 0; j < 4; j++) bf[j] = *(const bf16x8*)&bh[(wn + j*16 + lo16)*32 + quad*8];
      #pragma unroll
      for (int i = 0; i < MI; i++)
        #pragma unroll
        for (int j = 0; j < 4; j++)
          acc[i][j] = __builtin_amdgcn_mfma_f32_16x16x32_bf16(af[i], bf[j], acc[i][j], 0, 0, 0);
    }
  }
  #pragma unroll
  for (int j = 0; j < 4; j++) {
    int col = n0 + wn + j*16 + lo16;
    float bv = bias[col];
    #pragma unroll
    for (int i = 0; i < MI; i++) {
      #pragma unroll
      for (int r = 0; r < 4; r++) {
        int row = m0 + wm + i*16 + quad*4 + r;
        float v = acc[i][j][r] + bv;
        if (EPI == 1) {
          float u = 0.7978845608028654f*(v + 0.044715f*v*v*v);
          float e = __expf(2.0f*u);
          float th = (e - 1.0f) / (e + 1.0f);
          ((u16*)out)[(size_t)row*N + col] = f2b(0.5f*v*(1.0f + th));
        } else if (EPI == 2) {
          ((float*)out)[(size_t)row*N + col] = v + resid[(size_t)row*N + col];
        } else {
          ((float*)out)[(size_t)row*N + col] = v;
        }
      }
    }
  }
}

// ---------------- fallback GEMM (fp32 weights, 64x64 tile) ----------------
template<int EPI>
__global__ __launch_bounds__(256) void k_gemm(
    const u16* __restrict__ A, const float* __restrict__ Bw,
    const float* __restrict__ bias, const float* resid,
    void* out, int M, int N, int K)
{
  __shared__ alignas(16) u16 alds[64][40];
  __shared__ alignas(16) u16 blds[64][40];
  const int m0 = blockIdx.x * 64, n0b = blockIdx.y * 64;
  const int tid = threadIdx.x;
  const int wave = tid >> 6, lane = tid & 63, lo16 = lane & 15, quad = lane >> 4;
  f32x4 acc[4] = {{0,0,0,0},{0,0,0,0},{0,0,0,0},{0,0,0,0}};
  const int ar = tid >> 2, ac = (tid & 3) * 8;
  const int bk = tid >> 3, bn = (tid & 7) * 8;
  for (int k0 = 0; k0 < K; k0 += 32) {
    __syncthreads();
    *(bf16x8*)&alds[ar][ac] = *(const bf16x8*)(A + (size_t)(m0+ar)*K + k0 + ac);
    {
      const float* brow = Bw + (size_t)(k0+bk)*N + n0b + bn;
      f32x4 f0 = *(const f32x4*)brow;
      f32x4 f1 = *(const f32x4*)(brow + 4);
      #pragma unroll
      for (int i = 0; i < 4; i++) {
        blds[bn+i][bk]   = f2b(f0[i]);
        blds[bn+4+i][bk] = f2b(f1[i]);
      }
    }
    __syncthreads();
    bf16x8 af = *(const bf16x8*)&alds[wave*16 + lo16][quad*8];
    #pragma unroll
    for (int n = 0; n < 4; n++) {
      bf16x8 bf = *(const bf16x8*)&blds[n*16 + lo16][quad*8];
      acc[n] = __builtin_amdgcn_mfma_f32_16x16x32_bf16(af, bf, acc[n], 0, 0, 0);
    }
  }
  const int rbase = m0 + wave*16 + quad*4;
  #pragma unroll
  for (int n = 0; n < 4; n++) {
    int col = n0b + n*16 + lo16;
    float bv = bias[col];
    #pragma unroll
    for (int r = 0; r < 4; r++) {
      int row = rbase + r;
      float v = acc[n][r] + bv;
      if (EPI == 1) {
        float x3 = v*v*v;
        v = 0.5f*v*(1.0f + tanhf(0.7978845608028654f*(v + 0.044715f*x3)));
        ((u16*)out)[(size_t)row*N + col] = f2b(v);
      } else if (EPI == 2) {
        ((float*)out)[(size_t)row*N + col] = v + resid[(size_t)row*N + col];
      } else {
        ((float*)out)[(size_t)row*N + col] = v;
      }
    }
  }
}

extern "C" void kernel_launch(void* const* d_in, const int* in_sizes, int n_in,
                              void* d_out, int out_size, void* d_ws, size_t ws_size,
                              hipStream_t stream)
{
  (void)in_sizes; (void)n_in; (void)out_size;
  const int*   tokens  = (const int*)d_in[0];
  const int*   actions = (const int*)d_in[1];
  const float* emb     = (const float*)d_in[2];
  const float* act_emb = (const float*)d_in[3];
  const float* ln1_g   = (const float*)d_in[4];
  const float* ln1_b   = (const float*)d_in[5];
  const float* Wq      = (const float*)d_in[6];
  const float* Wk      = (const float*)d_in[7];
  const float* Wv      = (const float*)d_in[8];
  const float* Wo      = (const float*)d_in[9];
  const float* bo      = (const float*)d_in[10];
  const float* ln2_g   = (const float*)d_in[11];
  const float* ln2_b   = (const float*)d_in[12];
  const float* W1      = (const float*)d_in[13];
  const float* b1      = (const float*)d_in[14];
  const float* W2      = (const float*)d_in[15];
  const float* b2      = (const float*)d_in[16];
  const float* lnf_g   = (const float*)d_in[17];
  const float* lnf_b   = (const float*)d_in[18];
  const float* Wout    = (const float*)d_in[19];
  const float* bout    = (const float*)d_in[20];

  char* p = (char*)d_ws;
  float* abuf = (float*)p;  p += (size_t)NB*NCONDV*4;
  float* gbuf = (float*)p;  p += (size_t)34*NB*ND*4;
  float* xbuf = (float*)p;  p += (size_t)NTOK*ND*4;
  u16*   hbuf = (u16*)p;    p += (size_t)NTOK*ND*2;
  u16*   region = (u16*)p;
  u16* qbuf = region;
  u16* kbuf = region + (size_t)NTOK*ND;
  u16* vbuf = region + (size_t)2*NTOK*ND;
  u16* obuf = (u16*)d_out;

  size_t base = (size_t)(p - (char*)d_ws) + (size_t)3*NTOK*ND*2;
  size_t hid_sz = (size_t)NTOK*3072*2;
  size_t woT_sz = (size_t)NL*ND*ND*2;
  size_t w1T_sz = (size_t)NL*ND*3072*2;
  size_t w2T_sz = (size_t)NL*3072*ND*2;
  size_t woutT_sz = (size_t)ND*NV*2;
  size_t req_fast = base + hid_sz + woT_sz + w1T_sz + w2T_sz + woutT_sz;
  const bool fast = (ws_size >= req_fast);

  // one-time opt-in for large dynamic LDS on the pipelined GEMMs
  static int g8 = -1;
  if (g8 < 0) {
    bool ok = true;
    ok = ok && (hipFuncSetAttribute(reinterpret_cast<const void*>(k_gemm3<0>),
                hipFuncAttributeMaxDynamicSharedMemorySize, 147456) == hipSuccess);
    ok = ok && (hipFuncSetAttribute(reinterpret_cast<const void*>(k_gemm3<1>),
                hipFuncAttributeMaxDynamicSharedMemorySize, 147456) == hipSuccess);
    ok = ok && (hipFuncSetAttribute(reinterpret_cast<const void*>(k_gemm3<2>),
                hipFuncAttributeMaxDynamicSharedMemorySize, 147456) == hipSuccess);
    ok = ok && (hipFuncSetAttribute(reinterpret_cast<const void*>(k_gemm4<1>),
                hipFuncAttributeMaxDynamicSharedMemorySize, 131072) == hipSuccess);
    g8 = ok ? 1 : 0;
  }

  k_embed <<<NTOK, 256, 0, stream>>>(tokens, emb, xbuf);
  k_actvec<<<NB, 256, 0, stream>>>(actions, act_emb, abuf);
  k_gains <<<dim3(34,3), 256, 0, stream>>>(abuf, ln1_g, ln1_b, ln2_g, ln2_b, lnf_g, lnf_b, gbuf);

  if (fast) {
    char* q2 = (char*)d_ws + base;
    u16* hidbuf = (u16*)q2;  q2 += hid_sz;
    u16* WoT   = (u16*)q2;   q2 += woT_sz;
    u16* W1T   = (u16*)q2;   q2 += w1T_sz;
    u16* W2T   = (u16*)q2;   q2 += w2T_sz;
    u16* WoutT = (u16*)q2;

    k_wprep<<<dim3(ND/64, ND/64, NL), 256, 0, stream>>>(Wo, WoT, ND, ND);
    k_wprep<<<dim3(ND/64, 3072/64, NL), 256, 0, stream>>>(W1, W1T, ND, 3072);
    k_wprep<<<dim3(3072/64, ND/64, NL), 256, 0, stream>>>(W2, W2T, 3072, ND);
    k_wprep<<<dim3(ND/64, NV/64, 1), 256, 0, stream>>>(Wout, WoutT, ND, NV);

    for (int l = 0; l < NL; l++) {
      k_cln<<<NTOK/4, 256, 0, stream>>>(xbuf, gbuf + (size_t)(l*4+0)*NB*ND, gbuf + (size_t)(l*4+1)*NB*ND, hbuf);
      k_qkv<<<dim3(NTOK/64, NH, 3), 256, 0, stream>>>(hbuf,
          Wq + (size_t)l*NH*NDH*NDH, Wk + (size_t)l*NH*NDH*NDH, Wv + (size_t)l*NH*NDH*NDH,
          qbuf, kbuf, vbuf);
      k_attn2<<<dim3(NB*NH, NS/64), 256, 0, stream>>>(qbuf, kbuf, vbuf, obuf);
      if (g8) {
        k_gemm3<2><<<dim3((NTOK/256)*(ND/128)), 512, 147456, stream>>>(
            obuf, WoT + (size_t)l*ND*ND, bo + (size_t)l*ND, xbuf, xbuf, NTOK, ND, ND);
      } else {
        k_gemm_t<2,64><<<dim3(NTOK/64, ND/128), 256, 0, stream>>>(obuf, WoT + (size_t)l*ND*ND,
            bo + (size_t)l*ND, xbuf, xbuf, NTOK, ND, ND);
      }
      k_cln<<<NTOK/4, 256, 0, stream>>>(xbuf, gbuf + (size_t)(l*4+2)*NB*ND, gbuf + (size_t)(l*4+3)*NB*ND, hbuf);
      if (g8) {
        k_gemm4<1><<<dim3((NTOK/256)*(3072/256)), 512, 131072, stream>>>(
            hbuf, W1T + (size_t)l*ND*3072, b1 + (size_t)l*3072, nullptr, hidbuf, NTOK, 3072, ND);
        k_gemm3<2><<<dim3((NTOK/256)*(ND/128)), 512, 147456, stream>>>(
            hidbuf, W2T + (size_t)l*3072*ND, b2 + (size_t)l*ND, xbuf, xbuf, NTOK, ND, 3072);
      } else {
        k_gemm_t<1,128><<<dim3(NTOK/128, 3072/128), 256, 0, stream>>>(hbuf, W1T + (size_t)l*ND*3072,
            b1 + (size_t)l*3072, nullptr, hidbuf, NTOK, 3072, ND);
        k_gemm_t<2,64><<<dim3(NTOK/64, ND/128), 256, 0, stream>>>(hidbuf, W2T + (size_t)l*3072*ND,
            b2 + (size_t)l*ND, xbuf, xbuf, NTOK, ND, 3072);
      }
    }
    k_cln<<<NTOK/4, 256, 0, stream>>>(xbuf, gbuf + (size_t)32*NB*ND, gbuf + (size_t)33*NB*ND, hbuf);
    if (g8) {
      k_gemm3<0><<<dim3((NTOK/256)*(NV/128)), 512, 147456, stream>>>(
          hbuf, WoutT, bout, nullptr, (float*)d_out, NTOK, NV, ND);
    } else {
      k_gemm_t<0,64><<<dim3(NTOK/64, NV/128), 256, 0, stream>>>(hbuf, WoutT, bout, nullptr, (float*)d_out, NTOK, NV, ND);
    }
  } else {
    u16* hidbuf = region;
    for (int l = 0; l < NL; l++) {
      k_cln<<<NTOK/4, 256, 0, stream>>>(xbuf, gbuf + (size_t)(l*4+0)*NB*ND, gbuf + (size_t)(l*4+1)*NB*ND, hbuf);
      k_qkv<<<dim3(NTOK/64, NH, 3), 256, 0, stream>>>(hbuf,
          Wq + (size_t)l*NH*NDH*NDH, Wk + (size_t)l*NH*NDH*NDH, Wv + (size_t)l*NH*NDH*NDH,
          qbuf, kbuf, vbuf);
      k_attn2<<<dim3(NB*NH, NS/64), 256, 0, stream>>>(qbuf, kbuf, vbuf, obuf);
      k_gemm<2><<<dim3(NTOK/64, ND/64), 256, 0, stream>>>(obuf, Wo + (size_t)l*ND*ND,
          bo + (size_t)l*ND, xbuf, xbuf, NTOK, ND, ND);
      k_cln<<<NTOK/4, 256, 0, stream>>>(xbuf, gbuf + (size_t)(l*4+2)*NB*ND, gbuf + (size_t)(l*4+3)*NB*ND, hbuf);
      for (int c = 0; c < 2; c++) {
        const size_t mo = (size_t)c * 4096;
        k_gemm<1><<<dim3(4096/64, 3072/64), 256, 0, stream>>>(hbuf + mo*ND, W1 + (size_t)l*ND*3072,
            b1 + (size_t)l*3072, nullptr, hidbuf, 4096, 3072, ND);
        k_gemm<2><<<dim3(4096/64, ND/64), 256, 0, stream>>>(hidbuf, W2 + (size_t)l*3072*ND,
            b2 + (size_t)l*ND, xbuf + mo*ND, xbuf + mo*ND, 4096, ND, 3072);
      }
    }
    k_cln<<<NTOK/4, 256, 0, stream>>>(xbuf, gbuf + (size_t)32*NB*ND, gbuf + (size_t)33*NB*ND, hbuf);
    k_gemm<0><<<dim3(NTOK/64, NV/64), 256, 0, stream>>>(hbuf, Wout, bout, nullptr, (float*)d_out, NTOK, NV, ND);
  }
}

// Round 5
// 2403.843 us; speedup vs baseline: 1.0171x; 1.0171x over previous
//
#include <hip/hip_runtime.h>
#include <hip/hip_bf16.h>

typedef unsigned short u16;
typedef __attribute__((ext_vector_type(8))) short bf16x8;
typedef __attribute__((ext_vector_type(4))) float f32x4;

#define NB 8
#define NS 1024
#define ND 768
#define NH 12
#define NL 8
#define NDH 64
#define NV 1024
#define NCONDV 256
#define NTOK (NB*NS)

union BF8 { bf16x8 v; u16 u[8]; };
union US4 { ushort4 v; u16 u[4]; };

__device__ __forceinline__ float b2f(u16 u){ return __uint_as_float(((unsigned)u) << 16); }
__device__ __forceinline__ u16 f2b(float f){
  unsigned u = __float_as_uint(f);
  return (u16)((u + 0x7fffu + ((u >> 16) & 1u)) >> 16);   // RNE, finite inputs only
}

__device__ __forceinline__ void glds16(const u16* g, u16* l) {
  __builtin_amdgcn_global_load_lds((const __attribute__((address_space(1))) void*)g,
                                   (__attribute__((address_space(3))) void*)l, 16, 0, 0);
}

#define MEMFENCE asm volatile("" ::: "memory")

// ---------------- embedding + sinusoidal PE -> x fp32 ----------------
__global__ __launch_bounds__(256) void k_embed(const int* __restrict__ tokens,
                                               const float* __restrict__ emb,
                                               float* __restrict__ x)
{
  const int t = blockIdx.x;
  const int s = t & (NS - 1);
  const int tok = tokens[t];
  const float c = (float)(-9.210340371976184 / 768.0);
  for (int d = threadIdx.x; d < ND; d += 256) {
    float div = expf((float)(d & ~1) * c);
    float ang = (float)s * div;
    float pe = (d & 1) ? cosf(ang) : sinf(ang);
    x[(size_t)t*ND + d] = emb[(size_t)tok*ND + d] + pe;
  }
}

// ---------------- action vector ----------------
__global__ __launch_bounds__(256) void k_actvec(const int* __restrict__ actions,
                                                const float* __restrict__ act_emb,
                                                float* __restrict__ a)
{
  const int b = blockIdx.x, j = threadIdx.x;
  const int i = j >> 6, kk = j & 63;
  const int act = actions[b*4 + i];
  a[b*NCONDV + j] = act_emb[(size_t)act*64 + kk];
}

// ---------------- conditional LN gains ----------------
__global__ __launch_bounds__(256) void k_gains(const float* __restrict__ a,
    const float* __restrict__ g1, const float* __restrict__ b1,
    const float* __restrict__ g2, const float* __restrict__ b2,
    const float* __restrict__ gf, const float* __restrict__ bfp,
    float* __restrict__ outp)
{
  __shared__ float sa[NB*NCONDV];
  const int m = blockIdx.x, dc = blockIdx.y;
  for (int i = threadIdx.x; i < NB*NCONDV; i += 256) sa[i] = a[i];
  __syncthreads();
  const float* W;
  if (m < 32) {
    int ll = m >> 2, w = m & 3;
    const float* base = (w==0) ? g1 : (w==1) ? b1 : (w==2) ? g2 : b2;
    W = base + (size_t)ll * NCONDV * ND;
  } else {
    W = (m == 32) ? gf : bfp;
  }
  const int d = dc*256 + threadIdx.x;
  float acc[NB] = {0,0,0,0,0,0,0,0};
  for (int j = 0; j < NCONDV; j++) {
    float w = W[(size_t)j*ND + d];
    #pragma unroll
    for (int bb = 0; bb < NB; bb++) acc[bb] += sa[bb*NCONDV + j] * w;
  }
  #pragma unroll
  for (int bb = 0; bb < NB; bb++) outp[((size_t)m*NB + bb)*ND + d] = acc[bb];
}

// ---------------- conditional layernorm: one wave per token, no barriers ----------------
__global__ __launch_bounds__(256) void k_cln(const float* __restrict__ x,
                                             const float* __restrict__ g,
                                             const float* __restrict__ bb,
                                             u16* __restrict__ h)
{
  const int tid = threadIdx.x, w = tid >> 6, lane = tid & 63;
  const int t = blockIdx.x*4 + w;
  const int bi = t >> 10;
  const float* xr = x + (size_t)t*ND;
  f32x4 v0 = *(const f32x4*)(xr + lane*4);
  f32x4 v1 = *(const f32x4*)(xr + 256 + lane*4);
  f32x4 v2 = *(const f32x4*)(xr + 512 + lane*4);
  float s = (v0[0]+v0[1]+v0[2]+v0[3]) + (v1[0]+v1[1]+v1[2]+v1[3]) + (v2[0]+v2[1]+v2[2]+v2[3]);
  #pragma unroll
  for (int off = 1; off < 64; off <<= 1) s += __shfl_xor(s, off);
  float mu = s * (1.0f/768.0f);
  float s2 = 0.f;
  #pragma unroll
  for (int i = 0; i < 4; i++) { v0[i] -= mu; s2 += v0[i]*v0[i]; }
  #pragma unroll
  for (int i = 0; i < 4; i++) { v1[i] -= mu; s2 += v1[i]*v1[i]; }
  #pragma unroll
  for (int i = 0; i < 4; i++) { v2[i] -= mu; s2 += v2[i]*v2[i]; }
  #pragma unroll
  for (int off = 1; off < 64; off <<= 1) s2 += __shfl_xor(s2, off);
  float rs = rsqrtf(s2 * (1.0f/768.0f) + 1e-5f);
  const float* gr = g + (size_t)bi*ND;
  const float* br = bb + (size_t)bi*ND;
  u16* hr = h + (size_t)t*ND;
  #pragma unroll
  for (int j = 0; j < 3; j++) {
    f32x4 vv = (j==0) ? v0 : (j==1) ? v1 : v2;
    f32x4 gg = *(const f32x4*)(gr + j*256 + lane*4);
    f32x4 bv = *(const f32x4*)(br + j*256 + lane*4);
    US4 o;
    #pragma unroll
    for (int i = 0; i < 4; i++) o.u[i] = f2b(vv[i]*rs*gg[i] + bv[i]);
    *(ushort4*)(hr + j*256 + lane*4) = o.v;
  }
}

// ---------------- weight prep: fp32 [K][N] (xL) -> bf16 [N][K] ----------------
__global__ __launch_bounds__(256) void k_wprep(const float* __restrict__ src,
                                               u16* __restrict__ dst, int K, int N)
{
  __shared__ u16 t[64][65];
  const int k0 = blockIdx.x*64, n0 = blockIdx.y*64;
  const size_t mz = (size_t)blockIdx.z * K * N;
  src += mz; dst += mz;
  {
    int r = threadIdx.x >> 2, c0 = (threadIdx.x & 3) * 16;
    const float* s = src + (size_t)(k0 + r)*N + n0 + c0;
    f32x4 a = *(const f32x4*)s, b = *(const f32x4*)(s+4);
    f32x4 c = *(const f32x4*)(s+8), d = *(const f32x4*)(s+12);
    #pragma unroll
    for (int i = 0; i < 4; i++) {
      t[r][c0+i]    = f2b(a[i]);
      t[r][c0+4+i]  = f2b(b[i]);
      t[r][c0+8+i]  = f2b(c[i]);
      t[r][c0+12+i] = f2b(d[i]);
    }
  }
  __syncthreads();
  {
    int rn = threadIdx.x >> 2, kc = (threadIdx.x & 3)*16;
    u16* dp = dst + (size_t)(n0+rn)*K + k0 + kc;
    BF8 o0, o1;
    #pragma unroll
    for (int i = 0; i < 8; i++) { o0.u[i] = t[kc+i][rn]; o1.u[i] = t[kc+8+i][rn]; }
    *(bf16x8*)dp = o0.v; *(bf16x8*)(dp+8) = o1.v;
  }
}

// ---------------- fused per-head QKV projection: load h frags once, 3 weight mats ----------------
__global__ __launch_bounds__(256) void k_qkv(const u16* __restrict__ h,
    const float* __restrict__ Wq, const float* __restrict__ Wk, const float* __restrict__ Wv,
    u16* __restrict__ qo, u16* __restrict__ ko, u16* __restrict__ vo)
{
  __shared__ alignas(16) u16 wlds[3][64][72];
  const int t0 = blockIdx.x * 64, head = blockIdx.y;
  {
    int d = threadIdx.x >> 2, e0 = (threadIdx.x & 3) * 16;
    #pragma unroll
    for (int which = 0; which < 3; which++) {
      const float* W = ((which==0) ? Wq : (which==1) ? Wk : Wv) + (size_t)head*NDH*NDH;
      const float* wr = W + (size_t)d*NDH + e0;
      f32x4 f0 = *(const f32x4*)wr;
      f32x4 f1 = *(const f32x4*)(wr + 4);
      f32x4 f2 = *(const f32x4*)(wr + 8);
      f32x4 f3 = *(const f32x4*)(wr + 12);
      #pragma unroll
      for (int i = 0; i < 4; i++) {
        wlds[which][e0+i][d]    = f2b(f0[i]);
        wlds[which][e0+4+i][d]  = f2b(f1[i]);
        wlds[which][e0+8+i][d]  = f2b(f2[i]);
        wlds[which][e0+12+i][d] = f2b(f3[i]);
      }
    }
  }
  __syncthreads();
  const int wave = threadIdx.x >> 6, lane = threadIdx.x & 63;
  const int lo16 = lane & 15, quad = lane >> 4;
  const int arow = t0 + wave*16 + lo16;
  const u16* hr = h + (size_t)arow*ND + head*NDH + quad*8;
  bf16x8 a0 = *(const bf16x8*)hr;
  bf16x8 a1 = *(const bf16x8*)(hr + 32);
  #pragma unroll
  for (int which = 0; which < 3; which++) {
    f32x4 acc[4] = {{0,0,0,0},{0,0,0,0},{0,0,0,0},{0,0,0,0}};
    #pragma unroll
    for (int n = 0; n < 4; n++) {
      const u16* bp = &wlds[which][n*16 + lo16][quad*8];
      bf16x8 b0 = *(const bf16x8*)bp;
      bf16x8 b1 = *(const bf16x8*)(bp + 32);
      acc[n] = __builtin_amdgcn_mfma_f32_16x16x32_bf16(a0, b0, acc[n], 0, 0, 0);
      acc[n] = __builtin_amdgcn_mfma_f32_16x16x32_bf16(a1, b1, acc[n], 0, 0, 0);
    }
    #pragma unroll
    for (int n = 0; n < 4; n++) {
      #pragma unroll
      for (int r = 0; r < 4; r++) {
        int t = t0 + wave*16 + quad*4 + r;
        int bb = t >> 10, s = t & (NS-1);
        int e = n*16 + lo16;
        u16 val = f2b(acc[n][r]);
        if (which == 2) {
          int local = s & 127;
          int col = (s & ~127) | (((local & 15) << 3) | (local >> 4));
          vo[(((size_t)bb*NH + head)*NDH + e)*NS + col] = val;
        } else {
          u16* dst = (which == 0) ? qo : ko;
          dst[(((size_t)bb*NH + head)*NS + s)*NDH + e] = val;
        }
      }
    }
  }
}

// ---------------- flash attention: no-max softmax, slot-permuted P/V ----------------
// T14 async-stage, exp2 prescale on Q, v_cvt_pk_bf16_f32 P-packing.
__global__ __launch_bounds__(256) void k_attn2(const u16* __restrict__ q,
                                               const u16* __restrict__ kk,
                                               const u16* __restrict__ vt,
                                               u16* __restrict__ o)
{
  __shared__ alignas(16) u16 klds[128][72];
  __shared__ alignas(16) u16 vlds[64][136];
  __shared__ alignas(16) u16 plds[4][16][136];
  const int tid = threadIdx.x, w = tid >> 6, lane = tid & 63;
  const int lo16 = lane & 15, quad = lane >> 4;
  const int bh = blockIdx.x;
  const int b = bh / NH, head = bh - b*NH;
  const int q0 = blockIdx.y*64 + w*16;
  const u16* qb = q  + (size_t)bh*NS*NDH;
  const u16* kb = kk + (size_t)bh*NS*NDH;
  const u16* vb = vt + (size_t)bh*NDH*NS;
  BF8 aq0, aq1;
  {
    const u16* qr = qb + (size_t)(q0 + lo16)*NDH + quad*8;
    BF8 r0, r1; r0.v = *(const bf16x8*)qr; r1.v = *(const bf16x8*)(qr + 32);
    const float qs = 0.125f * 1.44269504088896f;   // fold log2(e): scores in log2 domain
    #pragma unroll
    for (int j = 0; j < 8; j++) {
      aq0.u[j] = f2b(b2f(r0.u[j]) * qs);
      aq1.u[j] = f2b(b2f(r1.u[j]) * qs);
    }
  }
  float lsum[4] = {0,0,0,0};
  f32x4 oacc[4] = {{0,0,0,0},{0,0,0,0},{0,0,0,0},{0,0,0,0}};

  bf16x8 kreg[4], vreg[4];
  #pragma unroll
  for (int i = 0; i < 4; i++) {
    int c = tid + 256*i;
    kreg[i] = *(const bf16x8*)(kb + (size_t)(c>>3)*NDH + (c&7)*8);
    vreg[i] = *(const bf16x8*)(vb + (size_t)(c>>4)*NS + (c&15)*8);
  }

  for (int kt = 0; kt < NS; kt += 128) {
    __syncthreads();
    #pragma unroll
    for (int i = 0; i < 4; i++) {
      int c = tid + 256*i;
      *(bf16x8*)&klds[c>>3][(c&7)*8] = kreg[i];
      *(bf16x8*)&vlds[c>>4][(c&15)*8] = vreg[i];
    }
    __syncthreads();
    if (kt + 128 < NS) {
      #pragma unroll
      for (int i = 0; i < 4; i++) {
        int c = tid + 256*i;
        kreg[i] = *(const bf16x8*)(kb + (size_t)(kt + 128 + (c>>3))*NDH + (c&7)*8);
        vreg[i] = *(const bf16x8*)(vb + (size_t)(c>>4)*NS + (kt + 128) + (c&15)*8);
      }
    }
    f32x4 s[8];
    #pragma unroll
    for (int j = 0; j < 8; j++) {
      const u16* kr = &klds[j*16 + lo16][quad*8];
      bf16x8 b0 = *(const bf16x8*)kr;
      bf16x8 b1 = *(const bf16x8*)(kr + 32);
      f32x4 z = {0,0,0,0};
      z = __builtin_amdgcn_mfma_f32_16x16x32_bf16(aq0.v, b0, z, 0, 0, 0);
      s[j] = __builtin_amdgcn_mfma_f32_16x16x32_bf16(aq1.v, b1, z, 0, 0, 0);
    }
    #pragma unroll
    for (int r = 0; r < 4; r++) {
      float p[8];
      #pragma unroll
      for (int j = 0; j < 8; j++) p[j] = exp2f(s[j][r]);
      unsigned pk32[4];
      #pragma unroll
      for (int j = 0; j < 4; j++)
        asm("v_cvt_pk_bf16_f32 %0, %1, %2" : "=v"(pk32[j]) : "v"(p[2*j]), "v"(p[2*j+1]));
      float ps = 0.f;
      #pragma unroll
      for (int j = 0; j < 4; j++) {
        ps += __uint_as_float(pk32[j] << 16);
        ps += __uint_as_float(pk32[j] & 0xffff0000u);
      }
      lsum[r] += ps;
      union { unsigned u[4]; bf16x8 v; } pkv;
      #pragma unroll
      for (int j = 0; j < 4; j++) pkv.u[j] = pk32[j];
      *(bf16x8*)&plds[w][quad*4 + r][lo16*8] = pkv.v;
    }
    #pragma unroll
    for (int kc = 0; kc < 4; kc++) {
      bf16x8 pa = *(const bf16x8*)&plds[w][lo16][kc*32 + quad*8];
      #pragma unroll
      for (int n = 0; n < 4; n++) {
        bf16x8 vf = *(const bf16x8*)&vlds[n*16 + lo16][kc*32 + quad*8];
        oacc[n] = __builtin_amdgcn_mfma_f32_16x16x32_bf16(pa, vf, oacc[n], 0, 0, 0);
      }
    }
  }
  #pragma unroll
  for (int r = 0; r < 4; r++) {
    #pragma unroll
    for (int off = 1; off < 16; off <<= 1) lsum[r] += __shfl_xor(lsum[r], off);
  }
  #pragma unroll
  for (int n = 0; n < 4; n++) {
    #pragma unroll
    for (int r = 0; r < 4; r++) {
      int s_ = q0 + quad*4 + r;
      int d = head*NDH + n*16 + lo16;
      o[((size_t)b*NS + s_)*ND + d] = f2b(oacc[n][r] / lsum[r]);
    }
  }
}

// ================= 256x256 fine-phase GEMM (m201 template port) =================
// 512 thr, 8 waves 2m(128) x 4n(64). LDS: 2 buffers x (A 256x64 + B 256x64) = 128KB.
// K-tile staged as 2 chunks: C_h = A rows [h*128,h*128+128) + B rows same (4 glds/thr).
// Per K-tile, 4 phases; chunk CH(t+1,0) issued in Ph0, CH(t+1,1) in Ph1 -> 2-4 phases
// of lead before the single vmcnt in read-free Ph3. Per phase: {ds_read subtile ||
// stage} -> barrier -> lgkmcnt(0)+sched_barrier -> setprio(1) 16 MFMA setprio(0) -> barrier.
// T2 swizzle identical to the ring. EPI 1: bf16=gelu(A@B+bias).
template<int EPI>
__global__ __launch_bounds__(512) void k_gemm5(
    const u16* __restrict__ A, const u16* __restrict__ Bt,
    const float* __restrict__ bias, const float* __restrict__ resid,
    void* __restrict__ out, int M, int N, int K)
{
  extern __shared__ u16 lds[];                 // 2 * 32768 u16
  const int tid = threadIdx.x;
  const int lane = tid & 63, lo16 = lane & 15, quad = lane >> 4;
  const int w = tid >> 6;
  const int wm = (w >> 2) << 7;                // 0,128
  const int wn = (w & 3) << 6;                 // 0,64,128,192

  const int nwg = (int)gridDim.x, flat = (int)blockIdx.x;
  const int swzid = ((nwg & 7) == 0) ? ((flat & 7) * (nwg >> 3) + (flat >> 3)) : flat;
  const int nbn = N >> 8;
  const int mb = swzid / nbn, nb = swzid - mb*nbn;
  const int m0 = mb << 8, n0 = nb << 8;
  const int NT = K >> 6;

  const int sr = tid >> 3, ss = tid & 7;       // sr 0..63, ss 0..7
  const int sg = ((ss ^ (sr & 7)) << 3);       // inverse-swizzled k-offset (u16)
  const u16* Asrc = A + (size_t)(m0 + sr) * K + sg;
  const u16* Bsrc = Bt + (size_t)(n0 + sr) * K + sg;
  u16* const sd = lds + tid * 8;               // = lds + sr*64 + ss*8 (linear)

  const int sw0 = ((quad ^ (lo16 & 7)) << 3);
  const int sw1 = (((4 + quad) ^ (lo16 & 7)) << 3);
  const int arow = (wm + lo16) << 6;
  const int brow = (wn + lo16) << 6;

  float bv[4];
  #pragma unroll
  for (int nf = 0; nf < 4; nf++) {
    bv[nf] = bias[n0 + wn + nf*16 + lo16];
    asm volatile("" :: "v"(bv[nf]));
  }

  f32x4 acc[8][4];
  #pragma unroll
  for (int i = 0; i < 8; i++)
    #pragma unroll
    for (int j = 0; j < 4; j++) acc[i][j] = (f32x4){0,0,0,0};

  auto CH = [&](int t, int h) {                // stage chunk h of tile t into buf t&1
    u16* dst = sd + ((t & 1) << 15) + (h << 13);
    const size_t ko = (size_t)t << 6;
    glds16(Asrc + ko + (size_t)(h*128)      * K, dst);
    glds16(Asrc + ko + (size_t)(h*128 + 64) * K, dst + 4096);
    glds16(Bsrc + ko + (size_t)(h*128)      * K, dst + 16384);
    glds16(Bsrc + ko + (size_t)(h*128 + 64) * K, dst + 16384 + 4096);
  };

  CH(0, 0); CH(0, 1);
  asm volatile("s_waitcnt vmcnt(0)" ::: "memory");
  __syncthreads();

  for (int t = 0; t < NT; t++) {
    const u16* cb = lds + ((t & 1) << 15);
    const bool pf = (t + 1 < NT);
    bf16x8 af[4][2], bfr[4][2];
    // ---- Ph0: af lo-half + bf[0-1]; stage CH(t+1,0); MFMA quadrant (lo, n0-1)
    #pragma unroll
    for (int mf = 0; mf < 4; mf++) {
      af[mf][0] = *(const bf16x8*)(cb + arow + mf*1024 + sw0);
      af[mf][1] = *(const bf16x8*)(cb + arow + mf*1024 + sw1);
    }
    #pragma unroll
    for (int nf = 0; nf < 2; nf++) {
      bfr[nf][0] = *(const bf16x8*)(cb + 16384 + brow + nf*1024 + sw0);
      bfr[nf][1] = *(const bf16x8*)(cb + 16384 + brow + nf*1024 + sw1);
    }
    if (pf) CH(t + 1, 0);
    __builtin_amdgcn_s_barrier();
    asm volatile("s_waitcnt lgkmcnt(0)" ::: "memory");
    __builtin_amdgcn_sched_barrier(0);
    __builtin_amdgcn_s_setprio(1);
    #pragma unroll
    for (int kk = 0; kk < 2; kk++)
      #pragma unroll
      for (int mf = 0; mf < 4; mf++)
        #pragma unroll
        for (int nf = 0; nf < 2; nf++)
          acc[mf][nf] = __builtin_amdgcn_mfma_f32_16x16x32_bf16(af[mf][kk], bfr[nf][kk], acc[mf][nf], 0, 0, 0);
    __builtin_amdgcn_s_setprio(0);
    __builtin_amdgcn_s_barrier();
    // ---- Ph1: bf[2-3]; stage CH(t+1,1); MFMA quadrant (lo, n2-3)
    #pragma unroll
    for (int nf = 2; nf < 4; nf++) {
      bfr[nf][0] = *(const bf16x8*)(cb + 16384 + brow + nf*1024 + sw0);
      bfr[nf][1] = *(const bf16x8*)(cb + 16384 + brow + nf*1024 + sw1);
    }
    if (pf) CH(t + 1, 1);
    __builtin_amdgcn_s_barrier();
    asm volatile("s_waitcnt lgkmcnt(0)" ::: "memory");
    __builtin_amdgcn_sched_barrier(0);
    __builtin_amdgcn_s_setprio(1);
    #pragma unroll
    for (int kk = 0; kk < 2; kk++)
      #pragma unroll
      for (int mf = 0; mf < 4; mf++)
        #pragma unroll
        for (int nf = 2; nf < 4; nf++)
          acc[mf][nf] = __builtin_amdgcn_mfma_f32_16x16x32_bf16(af[mf][kk], bfr[nf][kk], acc[mf][nf], 0, 0, 0);
    __builtin_amdgcn_s_setprio(0);
    __builtin_amdgcn_s_barrier();
    // ---- Ph2: af hi-half; MFMA quadrant (hi, n0-1)
    #pragma unroll
    for (int mf = 0; mf < 4; mf++) {
      af[mf][0] = *(const bf16x8*)(cb + arow + (4 + mf)*1024 + sw0);
      af[mf][1] = *(const bf16x8*)(cb + arow + (4 + mf)*1024 + sw1);
    }
    __builtin_amdgcn_s_barrier();
    asm volatile("s_waitcnt lgkmcnt(0)" ::: "memory");
    __builtin_amdgcn_sched_barrier(0);
    __builtin_amdgcn_s_setprio(1);
    #pragma unroll
    for (int kk = 0; kk < 2; kk++)
      #pragma unroll
      for (int mf = 0; mf < 4; mf++)
        #pragma unroll
        for (int nf = 0; nf < 2; nf++)
          acc[4 + mf][nf] = __builtin_amdgcn_mfma_f32_16x16x32_bf16(af[mf][kk], bfr[nf][kk], acc[4 + mf][nf], 0, 0, 0);
    __builtin_amdgcn_s_setprio(0);
    __builtin_amdgcn_s_barrier();
    // ---- Ph3 (read-free): vmcnt drain of tile t+1's chunks (2-4 phase lead), publish, MFMA (hi, n2-3)
    if (pf) { asm volatile("s_waitcnt vmcnt(0)" ::: "memory"); }
    __builtin_amdgcn_s_barrier();
    __builtin_amdgcn_s_setprio(1);
    #pragma unroll
    for (int kk = 0; kk < 2; kk++)
      #pragma unroll
      for (int mf = 0; mf < 4; mf++)
        #pragma unroll
        for (int nf = 2; nf < 4; nf++)
          acc[4 + mf][nf] = __builtin_amdgcn_mfma_f32_16x16x32_bf16(af[mf][kk], bfr[nf][kk], acc[4 + mf][nf], 0, 0, 0);
    __builtin_amdgcn_s_setprio(0);
  }

  // ---- epilogue
  #pragma unroll
  for (int fi = 0; fi < 8; fi++) {
    #pragma unroll
    for (int nf = 0; nf < 4; nf++) {
      const int col = n0 + wn + nf*16 + lo16;
      #pragma unroll
      for (int r = 0; r < 4; r++) {
        const int row = m0 + wm + fi*16 + quad*4 + r;
        const size_t idx = (size_t)row * N + col;
        float v = acc[fi][nf][r] + bv[nf];
        if (EPI == 1) {
          float u = 0.7978845608028654f*(v + 0.044715f*v*v*v);
          float e = __expf(2.0f*u);
          float th = (e - 1.0f) / (e + 1.0f);
          ((u16*)out)[idx] = f2b(0.5f*v*(1.0f + th));
        } else if (EPI == 2) {
          ((float*)out)[idx] = v + resid[idx];
        } else {
          ((float*)out)[idx] = v;
        }
      }
    }
  }
}

// ================= 256x128 GEMM, 3-stage LDS ring, 2 K-tiles in flight =================
// (proven round-3 kernel, unchanged) EPI 0: f32 ; 1: bf16 gelu ; 2: f32 + resid
template<int EPI>
__global__ __launch_bounds__(512) void k_gemm3(
    const u16* __restrict__ A, const u16* __restrict__ Bt,
    const float* __restrict__ bias, const float* __restrict__ resid,
    void* __restrict__ out, int M, int N, int K)
{
  extern __shared__ u16 lds[];                 // 3 * 24576 u16
  const int tid = threadIdx.x;
  const int lane = tid & 63, lo16 = lane & 15, quad = lane >> 4;
  const int w = tid >> 6;
  const int wm = (w & 3) << 6;                 // 0,64,128,192
  const int wn = (w >> 2) << 6;                // 0,64

  const int nwg = (int)gridDim.x, flat = (int)blockIdx.x;
  const int swzid = (flat & 7) * (nwg >> 3) + (flat >> 3);
  const int nbn = N >> 7;
  const int mb = swzid / nbn, nb = swzid - mb*nbn;
  const int m0 = mb << 8, n0 = nb << 7;
  const int NT = K >> 6;

  const int sr = tid >> 3, ss = tid & 7;
  const int sg = ((ss ^ (sr & 7)) << 3);
  const u16* Asrc = A + (size_t)(m0 + sr) * K + sg;
  const u16* Bsrc = Bt + (size_t)(n0 + sr) * K + sg;
  const size_t K64 = (size_t)K << 6;
  u16* const sd = lds + tid * 8;

  const int sw0 = ((quad ^ (lo16 & 7)) << 3);
  const int sw1 = (((4 + quad) ^ (lo16 & 7)) << 3);
  const int arow = (wm + lo16) << 6;
  const int brow = (wn + lo16) << 6;

  f32x4 acc[4][4];
  #pragma unroll
  for (int i = 0; i < 4; i++)
    #pragma unroll
    for (int j = 0; j < 4; j++) acc[i][j] = (f32x4){0,0,0,0};

  auto STAGE = [&](int t, int bi) {
    u16* dst = sd + bi * 24576;
    const size_t ko = (size_t)t << 6;
    #pragma unroll
    for (int c = 0; c < 4; c++) glds16(Asrc + ko + (size_t)c*K64, dst + c*4096);
    #pragma unroll
    for (int c = 0; c < 2; c++) glds16(Bsrc + ko + (size_t)c*K64, dst + 16384 + c*4096);
  };

  STAGE(0, 0);
  if (NT > 1) STAGE(1, 1);

  int cu = 0;
  for (int t = 0; t < NT; t++) {
    const int st = (cu == 0) ? 2 : cu - 1;
    MEMFENCE; __builtin_amdgcn_s_barrier(); MEMFENCE;
    if (t + 2 < NT) {
      STAGE(t + 2, st);
      asm volatile("s_waitcnt vmcnt(12)" ::: "memory");
    } else if (t + 1 < NT) {
      asm volatile("s_waitcnt vmcnt(6)" ::: "memory");
    } else {
      asm volatile("s_waitcnt vmcnt(0)" ::: "memory");
    }
    MEMFENCE; __builtin_amdgcn_s_barrier(); MEMFENCE;
    const u16* cb = lds + cu * 24576;
    bf16x8 af[4][2], bf[4][2];
    #pragma unroll
    for (int mf = 0; mf < 4; mf++) {
      af[mf][0] = *(const bf16x8*)(cb + arow + mf*1024 + sw0);
      af[mf][1] = *(const bf16x8*)(cb + arow + mf*1024 + sw1);
    }
    #pragma unroll
    for (int nf = 0; nf < 4; nf++) {
      bf[nf][0] = *(const bf16x8*)(cb + 16384 + brow + nf*1024 + sw0);
      bf[nf][1] = *(const bf16x8*)(cb + 16384 + brow + nf*1024 + sw1);
    }
    __builtin_amdgcn_s_setprio(1);
    #pragma unroll
    for (int kk = 0; kk < 2; kk++)
      #pragma unroll
      for (int mf = 0; mf < 4; mf++)
        #pragma unroll
        for (int nf = 0; nf < 4; nf++)
          acc[mf][nf] = __builtin_amdgcn_mfma_f32_16x16x32_bf16(af[mf][kk], bf[nf][kk], acc[mf][nf], 0, 0, 0);
    __builtin_amdgcn_s_setprio(0);
    cu = (cu == 2) ? 0 : cu + 1;
  }

  #pragma unroll
  for (int mf = 0; mf < 4; mf++) {
    #pragma unroll
    for (int nf = 0; nf < 4; nf++) {
      const int col = n0 + wn + nf*16 + lo16;
      const float bv = bias[col];
      #pragma unroll
      for (int r = 0; r < 4; r++) {
        const int row = m0 + wm + mf*16 + quad*4 + r;
        const size_t idx = (size_t)row * N + col;
        float v = acc[mf][nf][r] + bv;
        if (EPI == 1) {
          float u = 0.7978845608028654f*(v + 0.044715f*v*v*v);
          float e = __expf(2.0f*u);
          float th = (e - 1.0f) / (e + 1.0f);
          ((u16*)out)[idx] = f2b(0.5f*v*(1.0f + th));
        } else if (EPI == 2) {
          ((float*)out)[idx] = v + resid[idx];
        } else {
          ((float*)out)[idx] = v;
        }
      }
    }
  }
}

// ---------------- fast GEMM: MTx128 tile (fallback if dynamic-LDS opt-in refused) ----------------
template<int EPI, int MT>
__global__ __launch_bounds__(256) void k_gemm_t(
    const u16* __restrict__ A, const u16* __restrict__ Bt,
    const float* __restrict__ bias, const float* resid,
    void* out, int M, int N, int K)
{
  constexpr int MI = MT/32;
  __shared__ alignas(16) u16 alds[2*MT*32];
  __shared__ alignas(16) u16 blds[2*128*32];
  const int m0 = blockIdx.x*MT, n0 = blockIdx.y*128;
  const int tid = threadIdx.x;
  const int w = tid >> 6, lane = tid & 63, lo16 = lane & 15, quad = lane >> 4;
  const int wm = (w & 1)*(MT/2), wn = (w >> 1)*64;
  f32x4 acc[MI][4];
  #pragma unroll
  for (int i = 0; i < MI; i++)
    #pragma unroll
    for (int j = 0; j < 4; j++) acc[i][j] = (f32x4){0,0,0,0};
  const int r0 = tid >> 2, c0 = (tid & 3)*8;
  const u16* Ap = A  + (size_t)(m0 + r0)*K + c0;
  const u16* Bp = Bt + (size_t)(n0 + r0)*K + c0;
  for (int k0 = 0; k0 < K; k0 += 64) {
    __syncthreads();
    #pragma unroll
    for (int h = 0; h < 2; h++) {
      const int ho = h*32;
      glds16(Ap + k0 + ho, alds + h*(MT*32) + tid*8);
      if (MT == 128) glds16(Ap + (size_t)64*K + k0 + ho, alds + h*(MT*32) + 2048 + tid*8);
      glds16(Bp + k0 + ho, blds + h*4096 + tid*8);
      glds16(Bp + (size_t)64*K + k0 + ho, blds + h*4096 + 2048 + tid*8);
    }
    __syncthreads();
    #pragma unroll
    for (int h = 0; h < 2; h++) {
      const u16* ah = alds + h*(MT*32);
      const u16* bh = blds + h*4096;
      bf16x8 af[MI], bf[4];
      #pragma unroll
      for (int i = 0; i < MI; i++) af[i] = *(const bf16x8*)&ah[(wm + i*16 + lo16)*32 + quad*8];
      #pragma unroll
      for (int j = 0; j < 4; j++) bf[j] = *(const bf16x8*)&bh[(wn + j*16 + lo16)*32 + quad*8];
      #pragma unroll
      for (int i = 0; i < MI; i++)
        #pragma unroll
        for (int j = 0; j < 4; j++)
          acc[i][j] = __builtin_amdgcn_mfma_f32_16x16x32_bf16(af[i], bf[j], acc[i][j], 0, 0, 0);
    }
  }
  #pragma unroll
  for (int j = 0; j < 4; j++) {
    int col = n0 + wn + j*16 + lo16;
    float bv = bias[col];
    #pragma unroll
    for (int i = 0; i < MI; i++) {
      #pragma unroll
      for (int r = 0; r < 4; r++) {
        int row = m0 + wm + i*16 + quad*4 + r;
        float v = acc[i][j][r] + bv;
        if (EPI == 1) {
          float u = 0.7978845608028654f*(v + 0.044715f*v*v*v);
          float e = __expf(2.0f*u);
          float th = (e - 1.0f) / (e + 1.0f);
          ((u16*)out)[(size_t)row*N + col] = f2b(0.5f*v*(1.0f + th));
        } else if (EPI == 2) {
          ((float*)out)[(size_t)row*N + col] = v + resid[(size_t)row*N + col];
        } else {
          ((float*)out)[(size_t)row*N + col] = v;
        }
      }
    }
  }
}

// ---------------- fallback GEMM (fp32 weights, 64x64 tile) ----------------
template<int EPI>
__global__ __launch_bounds__(256) void k_gemm(
    const u16* __restrict__ A, const float* __restrict__ Bw,
    const float* __restrict__ bias, const float* resid,
    void* out, int M, int N, int K)
{
  __shared__ alignas(16) u16 alds[64][40];
  __shared__ alignas(16) u16 blds[64][40];
  const int m0 = blockIdx.x * 64, n0b = blockIdx.y * 64;
  const int tid = threadIdx.x;
  const int wave = tid >> 6, lane = tid & 63, lo16 = lane & 15, quad = lane >> 4;
  f32x4 acc[4] = {{0,0,0,0},{0,0,0,0},{0,0,0,0},{0,0,0,0}};
  const int ar = tid >> 2, ac = (tid & 3) * 8;
  const int bk = tid >> 3, bn = (tid & 7) * 8;
  for (int k0 = 0; k0 < K; k0 += 32) {
    __syncthreads();
    *(bf16x8*)&alds[ar][ac] = *(const bf16x8*)(A + (size_t)(m0+ar)*K + k0 + ac);
    {
      const float* brow = Bw + (size_t)(k0+bk)*N + n0b + bn;
      f32x4 f0 = *(const f32x4*)brow;
      f32x4 f1 = *(const f32x4*)(brow + 4);
      #pragma unroll
      for (int i = 0; i < 4; i++) {
        blds[bn+i][bk]   = f2b(f0[i]);
        blds[bn+4+i][bk] = f2b(f1[i]);
      }
    }
    __syncthreads();
    bf16x8 af = *(const bf16x8*)&alds[wave*16 + lo16][quad*8];
    #pragma unroll
    for (int n = 0; n < 4; n++) {
      bf16x8 bf = *(const bf16x8*)&blds[n*16 + lo16][quad*8];
      acc[n] = __builtin_amdgcn_mfma_f32_16x16x32_bf16(af, bf, acc[n], 0, 0, 0);
    }
  }
  const int rbase = m0 + wave*16 + quad*4;
  #pragma unroll
  for (int n = 0; n < 4; n++) {
    int col = n0b + n*16 + lo16;
    float bv = bias[col];
    #pragma unroll
    for (int r = 0; r < 4; r++) {
      int row = rbase + r;
      float v = acc[n][r] + bv;
      if (EPI == 1) {
        float x3 = v*v*v;
        v = 0.5f*v*(1.0f + tanhf(0.7978845608028654f*(v + 0.044715f*x3)));
        ((u16*)out)[(size_t)row*N + col] = f2b(v);
      } else if (EPI == 2) {
        ((float*)out)[(size_t)row*N + col] = v + resid[(size_t)row*N + col];
      } else {
        ((float*)out)[(size_t)row*N + col] = v;
      }
    }
  }
}

extern "C" void kernel_launch(void* const* d_in, const int* in_sizes, int n_in,
                              void* d_out, int out_size, void* d_ws, size_t ws_size,
                              hipStream_t stream)
{
  (void)in_sizes; (void)n_in; (void)out_size;
  const int*   tokens  = (const int*)d_in[0];
  const int*   actions = (const int*)d_in[1];
  const float* emb     = (const float*)d_in[2];
  const float* act_emb = (const float*)d_in[3];
  const float* ln1_g   = (const float*)d_in[4];
  const float* ln1_b   = (const float*)d_in[5];
  const float* Wq      = (const float*)d_in[6];
  const float* Wk      = (const float*)d_in[7];
  const float* Wv      = (const float*)d_in[8];
  const float* Wo      = (const float*)d_in[9];
  const float* bo      = (const float*)d_in[10];
  const float* ln2_g   = (const float*)d_in[11];
  const float* ln2_b   = (const float*)d_in[12];
  const float* W1      = (const float*)d_in[13];
  const float* b1      = (const float*)d_in[14];
  const float* W2      = (const float*)d_in[15];
  const float* b2      = (const float*)d_in[16];
  const float* lnf_g   = (const float*)d_in[17];
  const float* lnf_b   = (const float*)d_in[18];
  const float* Wout    = (const float*)d_in[19];
  const float* bout    = (const float*)d_in[20];

  char* p = (char*)d_ws;
  float* abuf = (float*)p;  p += (size_t)NB*NCONDV*4;
  float* gbuf = (float*)p;  p += (size_t)34*NB*ND*4;
  float* xbuf = (float*)p;  p += (size_t)NTOK*ND*4;
  u16*   hbuf = (u16*)p;    p += (size_t)NTOK*ND*2;
  u16*   region = (u16*)p;
  u16* qbuf = region;
  u16* kbuf = region + (size_t)NTOK*ND;
  u16* vbuf = region + (size_t)2*NTOK*ND;
  u16* obuf = (u16*)d_out;

  size_t base = (size_t)(p - (char*)d_ws) + (size_t)3*NTOK*ND*2;
  size_t hid_sz = (size_t)NTOK*3072*2;
  size_t woT_sz = (size_t)NL*ND*ND*2;
  size_t w1T_sz = (size_t)NL*ND*3072*2;
  size_t w2T_sz = (size_t)NL*3072*ND*2;
  size_t woutT_sz = (size_t)ND*NV*2;
  size_t req_fast = base + hid_sz + woT_sz + w1T_sz + w2T_sz + woutT_sz;
  const bool fast = (ws_size >= req_fast);

  // one-time opt-in for large dynamic LDS on the pipelined GEMMs
  static int g8 = -1;
  if (g8 < 0) {
    bool ok = true;
    ok = ok && (hipFuncSetAttribute(reinterpret_cast<const void*>(k_gemm3<0>),
                hipFuncAttributeMaxDynamicSharedMemorySize, 147456) == hipSuccess);
    ok = ok && (hipFuncSetAttribute(reinterpret_cast<const void*>(k_gemm3<2>),
                hipFuncAttributeMaxDynamicSharedMemorySize, 147456) == hipSuccess);
    ok = ok && (hipFuncSetAttribute(reinterpret_cast<const void*>(k_gemm5<1>),
                hipFuncAttributeMaxDynamicSharedMemorySize, 131072) == hipSuccess);
    g8 = ok ? 1 : 0;
  }

  k_embed <<<NTOK, 256, 0, stream>>>(tokens, emb, xbuf);
  k_actvec<<<NB, 256, 0, stream>>>(actions, act_emb, abuf);
  k_gains <<<dim3(34,3), 256, 0, stream>>>(abuf, ln1_g, ln1_b, ln2_g, ln2_b, lnf_g, lnf_b, gbuf);

  if (fast) {
    char* q2 = (char*)d_ws + base;
    u16* hidbuf = (u16*)q2;  q2 += hid_sz;
    u16* WoT   = (u16*)q2;   q2 += woT_sz;
    u16* W1T   = (u16*)q2;   q2 += w1T_sz;
    u16* W2T   = (u16*)q2;   q2 += w2T_sz;
    u16* WoutT = (u16*)q2;

    k_wprep<<<dim3(ND/64, ND/64, NL), 256, 0, stream>>>(Wo, WoT, ND, ND);
    k_wprep<<<dim3(ND/64, 3072/64, NL), 256, 0, stream>>>(W1, W1T, ND, 3072);
    k_wprep<<<dim3(3072/64, ND/64, NL), 256, 0, stream>>>(W2, W2T, 3072, ND);
    k_wprep<<<dim3(ND/64, NV/64, 1), 256, 0, stream>>>(Wout, WoutT, ND, NV);

    for (int l = 0; l < NL; l++) {
      k_cln<<<NTOK/4, 256, 0, stream>>>(xbuf, gbuf + (size_t)(l*4+0)*NB*ND, gbuf + (size_t)(l*4+1)*NB*ND, hbuf);
      k_qkv<<<dim3(NTOK/64, NH), 256, 0, stream>>>(hbuf,
          Wq + (size_t)l*NH*NDH*NDH, Wk + (size_t)l*NH*NDH*NDH, Wv + (size_t)l*NH*NDH*NDH,
          qbuf, kbuf, vbuf);
      k_attn2<<<dim3(NB*NH, NS/64), 256, 0, stream>>>(qbuf, kbuf, vbuf, obuf);
      if (g8) {
        k_gemm3<2><<<dim3((NTOK/256)*(ND/128)), 512, 147456, stream>>>(
            obuf, WoT + (size_t)l*ND*ND, bo + (size_t)l*ND, xbuf, xbuf, NTOK, ND, ND);
      } else {
        k_gemm_t<2,64><<<dim3(NTOK/64, ND/128), 256, 0, stream>>>(obuf, WoT + (size_t)l*ND*ND,
            bo + (size_t)l*ND, xbuf, xbuf, NTOK, ND, ND);
      }
      k_cln<<<NTOK/4, 256, 0, stream>>>(xbuf, gbuf + (size_t)(l*4+2)*NB*ND, gbuf + (size_t)(l*4+3)*NB*ND, hbuf);
      if (g8) {
        k_gemm5<1><<<dim3((NTOK/256)*(3072/256)), 512, 131072, stream>>>(
            hbuf, W1T + (size_t)l*ND*3072, b1 + (size_t)l*3072, nullptr, hidbuf, NTOK, 3072, ND);
        k_gemm3<2><<<dim3((NTOK/256)*(ND/128)), 512, 147456, stream>>>(
            hidbuf, W2T + (size_t)l*3072*ND, b2 + (size_t)l*ND, xbuf, xbuf, NTOK, ND, 3072);
      } else {
        k_gemm_t<1,128><<<dim3(NTOK/128, 3072/128), 256, 0, stream>>>(hbuf, W1T + (size_t)l*ND*3072,
            b1 + (size_t)l*3072, nullptr, hidbuf, NTOK, 3072, ND);
        k_gemm_t<2,64><<<dim3(NTOK/64, ND/128), 256, 0, stream>>>(hidbuf, W2T + (size_t)l*3072*ND,
            b2 + (size_t)l*ND, xbuf, xbuf, NTOK, ND, 3072);
      }
    }
    k_cln<<<NTOK/4, 256, 0, stream>>>(xbuf, gbuf + (size_t)32*NB*ND, gbuf + (size_t)33*NB*ND, hbuf);
    if (g8) {
      k_gemm3<0><<<dim3((NTOK/256)*(NV/128)), 512, 147456, stream>>>(
          hbuf, WoutT, bout, nullptr, (float*)d_out, NTOK, NV, ND);
    } else {
      k_gemm_t<0,64><<<dim3(NTOK/64, NV/128), 256, 0, stream>>>(hbuf, WoutT, bout, nullptr, (float*)d_out, NTOK, NV, ND);
    }
  } else {
    u16* hidbuf = region;
    for (int l = 0; l < NL; l++) {
      k_cln<<<NTOK/4, 256, 0, stream>>>(xbuf, gbuf + (size_t)(l*4+0)*NB*ND, gbuf + (size_t)(l*4+1)*NB*ND, hbuf);
      k_qkv<<<dim3(NTOK/64, NH), 256, 0, stream>>>(hbuf,
          Wq + (size_t)l*NH*NDH*NDH, Wk + (size_t)l*NH*NDH*NDH, Wv + (size_t)l*NH*NDH*NDH,
          qbuf, kbuf, vbuf);
      k_attn2<<<dim3(NB*NH, NS/64), 256, 0, stream>>>(qbuf, kbuf, vbuf, obuf);
      k_gemm<2><<<dim3(NTOK/64, ND/64), 256, 0, stream>>>(obuf, Wo + (size_t)l*ND*ND,
          bo + (size_t)l*ND, xbuf, xbuf, NTOK, ND, ND);
      k_cln<<<NTOK/4, 256, 0, stream>>>(xbuf, gbuf + (size_t)(l*4+2)*NB*ND, gbuf + (size_t)(l*4+3)*NB*ND, hbuf);
      for (int c = 0; c < 2; c++) {
        const size_t mo = (size_t)c * 4096;
        k_gemm<1><<<dim3(4096/64, 3072/64), 256, 0, stream>>>(hbuf + mo*ND, W1 + (size_t)l*ND*3072,
            b1 + (size_t)l*3072, nullptr, hidbuf, 4096, 3072, ND);
        k_gemm<2><<<dim3(4096/64, ND/64), 256, 0, stream>>>(hidbuf, W2 + (size_t)l*3072*ND,
            b2 + (size_t)l*ND, xbuf + mo*ND, xbuf + mo*ND, 4096, ND, 3072);
      }
    }
    k_cln<<<NTOK/4, 256, 0, stream>>>(xbuf, gbuf + (size_t)32*NB*ND, gbuf + (size_t)33*NB*ND, hbuf);
    k_gemm<0><<<dim3(NTOK/64, NV/64), 256, 0, stream>>>(hbuf, Wout, bout, nullptr, (float*)d_out, NTOK, NV, ND);
  }
}

// Round 6
// 2154.981 us; speedup vs baseline: 1.1346x; 1.1155x over previous
//
#include <hip/hip_runtime.h>
#include <hip/hip_bf16.h>

typedef unsigned short u16;
typedef __attribute__((ext_vector_type(8))) short bf16x8;
typedef __attribute__((ext_vector_type(4))) float f32x4;

#define NB 8
#define NS 1024
#define ND 768
#define NH 12
#define NL 8
#define NDH 64
#define NV 1024
#define NCONDV 256
#define NTOK (NB*NS)

union BF8 { bf16x8 v; u16 u[8]; };
union US4 { ushort4 v; u16 u[4]; };

__device__ __forceinline__ float b2f(u16 u){ return __uint_as_float(((unsigned)u) << 16); }
__device__ __forceinline__ u16 f2b(float f){
  unsigned u = __float_as_uint(f);
  return (u16)((u + 0x7fffu + ((u >> 16) & 1u)) >> 16);   // RNE, finite inputs only
}

__device__ __forceinline__ void glds16(const u16* g, u16* l) {
  __builtin_amdgcn_global_load_lds((const __attribute__((address_space(1))) void*)g,
                                   (__attribute__((address_space(3))) void*)l, 16, 0, 0);
}

#define MEMFENCE asm volatile("" ::: "memory")

// ---------------- embedding + sinusoidal PE -> x fp32 ----------------
__global__ __launch_bounds__(256) void k_embed(const int* __restrict__ tokens,
                                               const float* __restrict__ emb,
                                               float* __restrict__ x)
{
  const int t = blockIdx.x;
  const int s = t & (NS - 1);
  const int tok = tokens[t];
  const float c = (float)(-9.210340371976184 / 768.0);
  for (int d = threadIdx.x; d < ND; d += 256) {
    float div = expf((float)(d & ~1) * c);
    float ang = (float)s * div;
    float pe = (d & 1) ? cosf(ang) : sinf(ang);
    x[(size_t)t*ND + d] = emb[(size_t)tok*ND + d] + pe;
  }
}

// ---------------- action vector ----------------
__global__ __launch_bounds__(256) void k_actvec(const int* __restrict__ actions,
                                                const float* __restrict__ act_emb,
                                                float* __restrict__ a)
{
  const int b = blockIdx.x, j = threadIdx.x;
  const int i = j >> 6, kk = j & 63;
  const int act = actions[b*4 + i];
  a[b*NCONDV + j] = act_emb[(size_t)act*64 + kk];
}

// ---------------- conditional LN gains ----------------
__global__ __launch_bounds__(256) void k_gains(const float* __restrict__ a,
    const float* __restrict__ g1, const float* __restrict__ b1,
    const float* __restrict__ g2, const float* __restrict__ b2,
    const float* __restrict__ gf, const float* __restrict__ bfp,
    float* __restrict__ outp)
{
  __shared__ float sa[NB*NCONDV];
  const int m = blockIdx.x, dc = blockIdx.y;
  for (int i = threadIdx.x; i < NB*NCONDV; i += 256) sa[i] = a[i];
  __syncthreads();
  const float* W;
  if (m < 32) {
    int ll = m >> 2, w = m & 3;
    const float* base = (w==0) ? g1 : (w==1) ? b1 : (w==2) ? g2 : b2;
    W = base + (size_t)ll * NCONDV * ND;
  } else {
    W = (m == 32) ? gf : bfp;
  }
  const int d = dc*256 + threadIdx.x;
  float acc[NB] = {0,0,0,0,0,0,0,0};
  for (int j = 0; j < NCONDV; j++) {
    float w = W[(size_t)j*ND + d];
    #pragma unroll
    for (int bb = 0; bb < NB; bb++) acc[bb] += sa[bb*NCONDV + j] * w;
  }
  #pragma unroll
  for (int bb = 0; bb < NB; bb++) outp[((size_t)m*NB + bb)*ND + d] = acc[bb];
}

// ---------------- conditional layernorm: one wave per token, no barriers ----------------
__global__ __launch_bounds__(256) void k_cln(const float* __restrict__ x,
                                             const float* __restrict__ g,
                                             const float* __restrict__ bb,
                                             u16* __restrict__ h)
{
  const int tid = threadIdx.x, w = tid >> 6, lane = tid & 63;
  const int t = blockIdx.x*4 + w;
  const int bi = t >> 10;
  const float* xr = x + (size_t)t*ND;
  f32x4 v0 = *(const f32x4*)(xr + lane*4);
  f32x4 v1 = *(const f32x4*)(xr + 256 + lane*4);
  f32x4 v2 = *(const f32x4*)(xr + 512 + lane*4);
  float s = (v0[0]+v0[1]+v0[2]+v0[3]) + (v1[0]+v1[1]+v1[2]+v1[3]) + (v2[0]+v2[1]+v2[2]+v2[3]);
  #pragma unroll
  for (int off = 1; off < 64; off <<= 1) s += __shfl_xor(s, off);
  float mu = s * (1.0f/768.0f);
  float s2 = 0.f;
  #pragma unroll
  for (int i = 0; i < 4; i++) { v0[i] -= mu; s2 += v0[i]*v0[i]; }
  #pragma unroll
  for (int i = 0; i < 4; i++) { v1[i] -= mu; s2 += v1[i]*v1[i]; }
  #pragma unroll
  for (int i = 0; i < 4; i++) { v2[i] -= mu; s2 += v2[i]*v2[i]; }
  #pragma unroll
  for (int off = 1; off < 64; off <<= 1) s2 += __shfl_xor(s2, off);
  float rs = rsqrtf(s2 * (1.0f/768.0f) + 1e-5f);
  const float* gr = g + (size_t)bi*ND;
  const float* br = bb + (size_t)bi*ND;
  u16* hr = h + (size_t)t*ND;
  #pragma unroll
  for (int j = 0; j < 3; j++) {
    f32x4 vv = (j==0) ? v0 : (j==1) ? v1 : v2;
    f32x4 gg = *(const f32x4*)(gr + j*256 + lane*4);
    f32x4 bv = *(const f32x4*)(br + j*256 + lane*4);
    US4 o;
    #pragma unroll
    for (int i = 0; i < 4; i++) o.u[i] = f2b(vv[i]*rs*gg[i] + bv[i]);
    *(ushort4*)(hr + j*256 + lane*4) = o.v;
  }
}

// ---------------- weight prep: fp32 [K][N] (xL) -> bf16 [N][K] ----------------
__global__ __launch_bounds__(256) void k_wprep(const float* __restrict__ src,
                                               u16* __restrict__ dst, int K, int N)
{
  __shared__ u16 t[64][65];
  const int k0 = blockIdx.x*64, n0 = blockIdx.y*64;
  const size_t mz = (size_t)blockIdx.z * K * N;
  src += mz; dst += mz;
  {
    int r = threadIdx.x >> 2, c0 = (threadIdx.x & 3) * 16;
    const float* s = src + (size_t)(k0 + r)*N + n0 + c0;
    f32x4 a = *(const f32x4*)s, b = *(const f32x4*)(s+4);
    f32x4 c = *(const f32x4*)(s+8), d = *(const f32x4*)(s+12);
    #pragma unroll
    for (int i = 0; i < 4; i++) {
      t[r][c0+i]    = f2b(a[i]);
      t[r][c0+4+i]  = f2b(b[i]);
      t[r][c0+8+i]  = f2b(c[i]);
      t[r][c0+12+i] = f2b(d[i]);
    }
  }
  __syncthreads();
  {
    int rn = threadIdx.x >> 2, kc = (threadIdx.x & 3)*16;
    u16* dp = dst + (size_t)(n0+rn)*K + k0 + kc;
    BF8 o0, o1;
    #pragma unroll
    for (int i = 0; i < 8; i++) { o0.u[i] = t[kc+i][rn]; o1.u[i] = t[kc+8+i][rn]; }
    *(bf16x8*)dp = o0.v; *(bf16x8*)(dp+8) = o1.v;
  }
}

// ---------------- fused per-head QKV projection: load h frags once, 3 weight mats ----------------
__global__ __launch_bounds__(256) void k_qkv(const u16* __restrict__ h,
    const float* __restrict__ Wq, const float* __restrict__ Wk, const float* __restrict__ Wv,
    u16* __restrict__ qo, u16* __restrict__ ko, u16* __restrict__ vo)
{
  __shared__ alignas(16) u16 wlds[3][64][72];
  const int t0 = blockIdx.x * 64, head = blockIdx.y;
  {
    int d = threadIdx.x >> 2, e0 = (threadIdx.x & 3) * 16;
    #pragma unroll
    for (int which = 0; which < 3; which++) {
      const float* W = ((which==0) ? Wq : (which==1) ? Wk : Wv) + (size_t)head*NDH*NDH;
      const float* wr = W + (size_t)d*NDH + e0;
      f32x4 f0 = *(const f32x4*)wr;
      f32x4 f1 = *(const f32x4*)(wr + 4);
      f32x4 f2 = *(const f32x4*)(wr + 8);
      f32x4 f3 = *(const f32x4*)(wr + 12);
      #pragma unroll
      for (int i = 0; i < 4; i++) {
        wlds[which][e0+i][d]    = f2b(f0[i]);
        wlds[which][e0+4+i][d]  = f2b(f1[i]);
        wlds[which][e0+8+i][d]  = f2b(f2[i]);
        wlds[which][e0+12+i][d] = f2b(f3[i]);
      }
    }
  }
  __syncthreads();
  const int wave = threadIdx.x >> 6, lane = threadIdx.x & 63;
  const int lo16 = lane & 15, quad = lane >> 4;
  const int arow = t0 + wave*16 + lo16;
  const u16* hr = h + (size_t)arow*ND + head*NDH + quad*8;
  bf16x8 a0 = *(const bf16x8*)hr;
  bf16x8 a1 = *(const bf16x8*)(hr + 32);
  #pragma unroll
  for (int which = 0; which < 3; which++) {
    f32x4 acc[4] = {{0,0,0,0},{0,0,0,0},{0,0,0,0},{0,0,0,0}};
    #pragma unroll
    for (int n = 0; n < 4; n++) {
      const u16* bp = &wlds[which][n*16 + lo16][quad*8];
      bf16x8 b0 = *(const bf16x8*)bp;
      bf16x8 b1 = *(const bf16x8*)(bp + 32);
      acc[n] = __builtin_amdgcn_mfma_f32_16x16x32_bf16(a0, b0, acc[n], 0, 0, 0);
      acc[n] = __builtin_amdgcn_mfma_f32_16x16x32_bf16(a1, b1, acc[n], 0, 0, 0);
    }
    #pragma unroll
    for (int n = 0; n < 4; n++) {
      #pragma unroll
      for (int r = 0; r < 4; r++) {
        int t = t0 + wave*16 + quad*4 + r;
        int bb = t >> 10, s = t & (NS-1);
        int e = n*16 + lo16;
        u16 val = f2b(acc[n][r]);
        if (which == 2) {
          int local = s & 127;
          int col = (s & ~127) | (((local & 15) << 3) | (local >> 4));
          vo[(((size_t)bb*NH + head)*NDH + e)*NS + col] = val;
        } else {
          u16* dst = (which == 0) ? qo : ko;
          dst[(((size_t)bb*NH + head)*NS + s)*NDH + e] = val;
        }
      }
    }
  }
}

// ---------------- flash attention: no-max softmax, slot-permuted P/V ----------------
// T14 async-stage, exp2 prescale on Q, v_cvt_pk_bf16_f32 P-packing.
__global__ __launch_bounds__(256) void k_attn2(const u16* __restrict__ q,
                                               const u16* __restrict__ kk,
                                               const u16* __restrict__ vt,
                                               u16* __restrict__ o)
{
  __shared__ alignas(16) u16 klds[128][72];
  __shared__ alignas(16) u16 vlds[64][136];
  __shared__ alignas(16) u16 plds[4][16][136];
  const int tid = threadIdx.x, w = tid >> 6, lane = tid & 63;
  const int lo16 = lane & 15, quad = lane >> 4;
  const int bh = blockIdx.x;
  const int b = bh / NH, head = bh - b*NH;
  const int q0 = blockIdx.y*64 + w*16;
  const u16* qb = q  + (size_t)bh*NS*NDH;
  const u16* kb = kk + (size_t)bh*NS*NDH;
  const u16* vb = vt + (size_t)bh*NDH*NS;
  BF8 aq0, aq1;
  {
    const u16* qr = qb + (size_t)(q0 + lo16)*NDH + quad*8;
    BF8 r0, r1; r0.v = *(const bf16x8*)qr; r1.v = *(const bf16x8*)(qr + 32);
    const float qs = 0.125f * 1.44269504088896f;   // fold log2(e): scores in log2 domain
    #pragma unroll
    for (int j = 0; j < 8; j++) {
      aq0.u[j] = f2b(b2f(r0.u[j]) * qs);
      aq1.u[j] = f2b(b2f(r1.u[j]) * qs);
    }
  }
  float lsum[4] = {0,0,0,0};
  f32x4 oacc[4] = {{0,0,0,0},{0,0,0,0},{0,0,0,0},{0,0,0,0}};

  bf16x8 kreg[4], vreg[4];
  #pragma unroll
  for (int i = 0; i < 4; i++) {
    int c = tid + 256*i;
    kreg[i] = *(const bf16x8*)(kb + (size_t)(c>>3)*NDH + (c&7)*8);
    vreg[i] = *(const bf16x8*)(vb + (size_t)(c>>4)*NS + (c&15)*8);
  }

  for (int kt = 0; kt < NS; kt += 128) {
    __syncthreads();
    #pragma unroll
    for (int i = 0; i < 4; i++) {
      int c = tid + 256*i;
      *(bf16x8*)&klds[c>>3][(c&7)*8] = kreg[i];
      *(bf16x8*)&vlds[c>>4][(c&15)*8] = vreg[i];
    }
    __syncthreads();
    if (kt + 128 < NS) {
      #pragma unroll
      for (int i = 0; i < 4; i++) {
        int c = tid + 256*i;
        kreg[i] = *(const bf16x8*)(kb + (size_t)(kt + 128 + (c>>3))*NDH + (c&7)*8);
        vreg[i] = *(const bf16x8*)(vb + (size_t)(c>>4)*NS + (kt + 128) + (c&15)*8);
      }
    }
    f32x4 s[8];
    #pragma unroll
    for (int j = 0; j < 8; j++) {
      const u16* kr = &klds[j*16 + lo16][quad*8];
      bf16x8 b0 = *(const bf16x8*)kr;
      bf16x8 b1 = *(const bf16x8*)(kr + 32);
      f32x4 z = {0,0,0,0};
      z = __builtin_amdgcn_mfma_f32_16x16x32_bf16(aq0.v, b0, z, 0, 0, 0);
      s[j] = __builtin_amdgcn_mfma_f32_16x16x32_bf16(aq1.v, b1, z, 0, 0, 0);
    }
    #pragma unroll
    for (int r = 0; r < 4; r++) {
      float p[8];
      #pragma unroll
      for (int j = 0; j < 8; j++) p[j] = exp2f(s[j][r]);
      unsigned pk32[4];
      #pragma unroll
      for (int j = 0; j < 4; j++)
        asm("v_cvt_pk_bf16_f32 %0, %1, %2" : "=v"(pk32[j]) : "v"(p[2*j]), "v"(p[2*j+1]));
      float ps = 0.f;
      #pragma unroll
      for (int j = 0; j < 4; j++) {
        ps += __uint_as_float(pk32[j] << 16);
        ps += __uint_as_float(pk32[j] & 0xffff0000u);
      }
      lsum[r] += ps;
      union { unsigned u[4]; bf16x8 v; } pkv;
      #pragma unroll
      for (int j = 0; j < 4; j++) pkv.u[j] = pk32[j];
      *(bf16x8*)&plds[w][quad*4 + r][lo16*8] = pkv.v;
    }
    #pragma unroll
    for (int kc = 0; kc < 4; kc++) {
      bf16x8 pa = *(const bf16x8*)&plds[w][lo16][kc*32 + quad*8];
      #pragma unroll
      for (int n = 0; n < 4; n++) {
        bf16x8 vf = *(const bf16x8*)&vlds[n*16 + lo16][kc*32 + quad*8];
        oacc[n] = __builtin_amdgcn_mfma_f32_16x16x32_bf16(pa, vf, oacc[n], 0, 0, 0);
      }
    }
  }
  #pragma unroll
  for (int r = 0; r < 4; r++) {
    #pragma unroll
    for (int off = 1; off < 16; off <<= 1) lsum[r] += __shfl_xor(lsum[r], off);
  }
  #pragma unroll
  for (int n = 0; n < 4; n++) {
    #pragma unroll
    for (int r = 0; r < 4; r++) {
      int s_ = q0 + quad*4 + r;
      int d = head*NDH + n*16 + lo16;
      o[((size_t)b*NS + s_)*ND + d] = f2b(oacc[n][r] / lsum[r]);
    }
  }
}

// ================= 128x128 GEMM, 2 blocks/CU, double-buffered (m97-occupancy + T2) =================
// 256 thr, 4 waves 2x2 (64x64 C each). LDS: 2 stages x (A 128x64 + B 128x64) = 64KB STATIC
// -> 2 blocks/CU co-resident: when one block stalls at barrier/stage, the other's MFMA
// fills the pipe (m97/m114 implicit cross-block overlap — the piece all 1-block/CU
// variants were missing). Depth-1 prefetch, counted vmcnt(8) (never 0 in main loop),
// 2 barriers/K-tile. T2 swizzle: granule g of row r at slot g^(r&7), staged via linear
// glds dest + inverse-swizzled global source (rule 21); ds_read conflict-free (2-way max).
// T1 XCD swizzle on flat blockIdx. EPI 0: f32=A@B+bias ; 1: bf16=gelu ; 2: f32=+bias+resid
template<int EPI>
__global__ __launch_bounds__(256) void k_gemm6(
    const u16* __restrict__ A, const u16* __restrict__ Bt,
    const float* __restrict__ bias, const float* __restrict__ resid,
    void* __restrict__ out, int M, int N, int K)
{
  __shared__ alignas(16) u16 lds[2*16384];     // 64 KB: [stage][A 128x64 | B 128x64]
  const int tid = threadIdx.x;
  const int lane = tid & 63, lo16 = lane & 15, quad = lane >> 4;
  const int w = tid >> 6;
  const int wm = (w & 1) << 6;                 // 0,64
  const int wn = (w >> 1) << 6;                // 0,64

  // T1 XCD swizzle (grids %8 == 0)
  const int nwg = (int)gridDim.x, flat = (int)blockIdx.x;
  const int swzid = ((nwg & 7) == 0) ? ((flat & 7) * (nwg >> 3) + (flat >> 3)) : flat;
  const int nbn = N >> 7;
  const int mb = swzid / nbn, nb = swzid - mb*nbn;
  const int m0 = mb << 7, n0 = nb << 7;
  const int NT = K >> 6;

  // staging map: thread -> (row sr within 32-row chunk, 16B slot ss); LDS dest tid-linear.
  const int sr = tid >> 3, ss = tid & 7;       // sr 0..31, ss 0..7
  const int sg = ((ss ^ (sr & 7)) << 3);       // inverse-swizzled k-offset (u16)
  const u16* Asrc = A + (size_t)(m0 + sr) * K + sg;
  const u16* Bsrc = Bt + (size_t)(n0 + sr) * K + sg;
  const size_t K32 = (size_t)K << 5;           // 32 rows of u16
  u16* const sd = lds + tid * 8;               // linear within each 32-row chunk

  // compute-read swizzled granule offsets (u16) for kk=0/1
  const int sw0 = ((quad ^ (lo16 & 7)) << 3);
  const int sw1 = (((4 + quad) ^ (lo16 & 7)) << 3);
  const int arow = (wm + lo16) << 6;
  const int brow = (wn + lo16) << 6;

  // pre-load bias; keep-alive forces retirement so loop vmcnt counting stays exact
  float bv[4];
  #pragma unroll
  for (int nf = 0; nf < 4; nf++) {
    bv[nf] = bias[n0 + wn + nf*16 + lo16];
    asm volatile("" :: "v"(bv[nf]));
  }

  f32x4 acc[4][4];
  #pragma unroll
  for (int i = 0; i < 4; i++)
    #pragma unroll
    for (int j = 0; j < 4; j++) acc[i][j] = (f32x4){0,0,0,0};

  auto STAGE = [&](int t, int bi) {            // 8 glds16/thread: A 4 chunks + B 4 chunks
    u16* dst = sd + bi * 16384;
    const size_t ko = (size_t)t << 6;
    #pragma unroll
    for (int c = 0; c < 4; c++) glds16(Asrc + ko + (size_t)c*K32, dst + c*2048);
    #pragma unroll
    for (int c = 0; c < 4; c++) glds16(Bsrc + ko + (size_t)c*K32, dst + 8192 + c*2048);
  };

  STAGE(0, 0);
  for (int t = 0; t < NT; t++) {
    MEMFENCE; __builtin_amdgcn_s_barrier(); MEMFENCE;   // buf (t+1)&1 free (tile t-1 consumed)
    if (t + 1 < NT) {
      STAGE(t + 1, (t + 1) & 1);
      asm volatile("s_waitcnt vmcnt(8)" ::: "memory");  // my tile-t loads landed
    } else {
      asm volatile("s_waitcnt vmcnt(0)" ::: "memory");
    }
    MEMFENCE; __builtin_amdgcn_s_barrier(); MEMFENCE;   // everyone's tile-t loads landed
    const u16* cb = lds + (t & 1) * 16384;
    bf16x8 af[4][2], bf[4][2];
    #pragma unroll
    for (int mf = 0; mf < 4; mf++) {
      af[mf][0] = *(const bf16x8*)(cb + arow + mf*1024 + sw0);
      af[mf][1] = *(const bf16x8*)(cb + arow + mf*1024 + sw1);
    }
    #pragma unroll
    for (int nf = 0; nf < 4; nf++) {
      bf[nf][0] = *(const bf16x8*)(cb + 8192 + brow + nf*1024 + sw0);
      bf[nf][1] = *(const bf16x8*)(cb + 8192 + brow + nf*1024 + sw1);
    }
    __builtin_amdgcn_s_setprio(1);
    #pragma unroll
    for (int kk = 0; kk < 2; kk++)
      #pragma unroll
      for (int mf = 0; mf < 4; mf++)
        #pragma unroll
        for (int nf = 0; nf < 4; nf++)
          acc[mf][nf] = __builtin_amdgcn_mfma_f32_16x16x32_bf16(af[mf][kk], bf[nf][kk], acc[mf][nf], 0, 0, 0);
    __builtin_amdgcn_s_setprio(0);
  }

  // ---- epilogue
  #pragma unroll
  for (int mf = 0; mf < 4; mf++) {
    #pragma unroll
    for (int nf = 0; nf < 4; nf++) {
      const int col = n0 + wn + nf*16 + lo16;
      #pragma unroll
      for (int r = 0; r < 4; r++) {
        const int row = m0 + wm + mf*16 + quad*4 + r;
        const size_t idx = (size_t)row * N + col;
        float v = acc[mf][nf][r] + bv[nf];
        if (EPI == 1) {
          float u = 0.7978845608028654f*(v + 0.044715f*v*v*v);
          float e = __expf(2.0f*u);
          float th = (e - 1.0f) / (e + 1.0f);
          ((u16*)out)[idx] = f2b(0.5f*v*(1.0f + th));
        } else if (EPI == 2) {
          ((float*)out)[idx] = v + resid[idx];
        } else {
          ((float*)out)[idx] = v;
        }
      }
    }
  }
}

// ---------------- fallback GEMM (fp32 weights, 64x64 tile; small-workspace path) ----------------
template<int EPI>
__global__ __launch_bounds__(256) void k_gemm(
    const u16* __restrict__ A, const float* __restrict__ Bw,
    const float* __restrict__ bias, const float* resid,
    void* out, int M, int N, int K)
{
  __shared__ alignas(16) u16 alds[64][40];
  __shared__ alignas(16) u16 blds[64][40];
  const int m0 = blockIdx.x * 64, n0b = blockIdx.y * 64;
  const int tid = threadIdx.x;
  const int wave = tid >> 6, lane = tid & 63, lo16 = lane & 15, quad = lane >> 4;
  f32x4 acc[4] = {{0,0,0,0},{0,0,0,0},{0,0,0,0},{0,0,0,0}};
  const int ar = tid >> 2, ac = (tid & 3) * 8;
  const int bk = tid >> 3, bn = (tid & 7) * 8;
  for (int k0 = 0; k0 < K; k0 += 32) {
    __syncthreads();
    *(bf16x8*)&alds[ar][ac] = *(const bf16x8*)(A + (size_t)(m0+ar)*K + k0 + ac);
    {
      const float* brow = Bw + (size_t)(k0+bk)*N + n0b + bn;
      f32x4 f0 = *(const f32x4*)brow;
      f32x4 f1 = *(const f32x4*)(brow + 4);
      #pragma unroll
      for (int i = 0; i < 4; i++) {
        blds[bn+i][bk]   = f2b(f0[i]);
        blds[bn+4+i][bk] = f2b(f1[i]);
      }
    }
    __syncthreads();
    bf16x8 af = *(const bf16x8*)&alds[wave*16 + lo16][quad*8];
    #pragma unroll
    for (int n = 0; n < 4; n++) {
      bf16x8 bf = *(const bf16x8*)&blds[n*16 + lo16][quad*8];
      acc[n] = __builtin_amdgcn_mfma_f32_16x16x32_bf16(af, bf, acc[n], 0, 0, 0);
    }
  }
  const int rbase = m0 + wave*16 + quad*4;
  #pragma unroll
  for (int n = 0; n < 4; n++) {
    int col = n0b + n*16 + lo16;
    float bv = bias[col];
    #pragma unroll
    for (int r = 0; r < 4; r++) {
      int row = rbase + r;
      float v = acc[n][r] + bv;
      if (EPI == 1) {
        float x3 = v*v*v;
        v = 0.5f*v*(1.0f + tanhf(0.7978845608028654f*(v + 0.044715f*x3)));
        ((u16*)out)[(size_t)row*N + col] = f2b(v);
      } else if (EPI == 2) {
        ((float*)out)[(size_t)row*N + col] = v + resid[(size_t)row*N + col];
      } else {
        ((float*)out)[(size_t)row*N + col] = v;
      }
    }
  }
}

extern "C" void kernel_launch(void* const* d_in, const int* in_sizes, int n_in,
                              void* d_out, int out_size, void* d_ws, size_t ws_size,
                              hipStream_t stream)
{
  (void)in_sizes; (void)n_in; (void)out_size;
  const int*   tokens  = (const int*)d_in[0];
  const int*   actions = (const int*)d_in[1];
  const float* emb     = (const float*)d_in[2];
  const float* act_emb = (const float*)d_in[3];
  const float* ln1_g   = (const float*)d_in[4];
  const float* ln1_b   = (const float*)d_in[5];
  const float* Wq      = (const float*)d_in[6];
  const float* Wk      = (const float*)d_in[7];
  const float* Wv      = (const float*)d_in[8];
  const float* Wo      = (const float*)d_in[9];
  const float* bo      = (const float*)d_in[10];
  const float* ln2_g   = (const float*)d_in[11];
  const float* ln2_b   = (const float*)d_in[12];
  const float* W1      = (const float*)d_in[13];
  const float* b1      = (const float*)d_in[14];
  const float* W2      = (const float*)d_in[15];
  const float* b2      = (const float*)d_in[16];
  const float* lnf_g   = (const float*)d_in[17];
  const float* lnf_b   = (const float*)d_in[18];
  const float* Wout    = (const float*)d_in[19];
  const float* bout    = (const float*)d_in[20];

  char* p = (char*)d_ws;
  float* abuf = (float*)p;  p += (size_t)NB*NCONDV*4;
  float* gbuf = (float*)p;  p += (size_t)34*NB*ND*4;
  float* xbuf = (float*)p;  p += (size_t)NTOK*ND*4;
  u16*   hbuf = (u16*)p;    p += (size_t)NTOK*ND*2;
  u16*   region = (u16*)p;
  u16* qbuf = region;
  u16* kbuf = region + (size_t)NTOK*ND;
  u16* vbuf = region + (size_t)2*NTOK*ND;
  u16* obuf = (u16*)d_out;

  size_t base = (size_t)(p - (char*)d_ws) + (size_t)3*NTOK*ND*2;
  size_t hid_sz = (size_t)NTOK*3072*2;
  size_t woT_sz = (size_t)NL*ND*ND*2;
  size_t w1T_sz = (size_t)NL*ND*3072*2;
  size_t w2T_sz = (size_t)NL*3072*ND*2;
  size_t woutT_sz = (size_t)ND*NV*2;
  size_t req_fast = base + hid_sz + woT_sz + w1T_sz + w2T_sz + woutT_sz;
  const bool fast = (ws_size >= req_fast);

  k_embed <<<NTOK, 256, 0, stream>>>(tokens, emb, xbuf);
  k_actvec<<<NB, 256, 0, stream>>>(actions, act_emb, abuf);
  k_gains <<<dim3(34,3), 256, 0, stream>>>(abuf, ln1_g, ln1_b, ln2_g, ln2_b, lnf_g, lnf_b, gbuf);

  if (fast) {
    char* q2 = (char*)d_ws + base;
    u16* hidbuf = (u16*)q2;  q2 += hid_sz;
    u16* WoT   = (u16*)q2;   q2 += woT_sz;
    u16* W1T   = (u16*)q2;   q2 += w1T_sz;
    u16* W2T   = (u16*)q2;   q2 += w2T_sz;
    u16* WoutT = (u16*)q2;

    k_wprep<<<dim3(ND/64, ND/64, NL), 256, 0, stream>>>(Wo, WoT, ND, ND);
    k_wprep<<<dim3(ND/64, 3072/64, NL), 256, 0, stream>>>(W1, W1T, ND, 3072);
    k_wprep<<<dim3(3072/64, ND/64, NL), 256, 0, stream>>>(W2, W2T, 3072, ND);
    k_wprep<<<dim3(ND/64, NV/64, 1), 256, 0, stream>>>(Wout, WoutT, ND, NV);

    for (int l = 0; l < NL; l++) {
      k_cln<<<NTOK/4, 256, 0, stream>>>(xbuf, gbuf + (size_t)(l*4+0)*NB*ND, gbuf + (size_t)(l*4+1)*NB*ND, hbuf);
      k_qkv<<<dim3(NTOK/64, NH), 256, 0, stream>>>(hbuf,
          Wq + (size_t)l*NH*NDH*NDH, Wk + (size_t)l*NH*NDH*NDH, Wv + (size_t)l*NH*NDH*NDH,
          qbuf, kbuf, vbuf);
      k_attn2<<<dim3(NB*NH, NS/64), 256, 0, stream>>>(qbuf, kbuf, vbuf, obuf);
      k_gemm6<2><<<dim3((NTOK/128)*(ND/128)), 256, 0, stream>>>(
          obuf, WoT + (size_t)l*ND*ND, bo + (size_t)l*ND, xbuf, xbuf, NTOK, ND, ND);
      k_cln<<<NTOK/4, 256, 0, stream>>>(xbuf, gbuf + (size_t)(l*4+2)*NB*ND, gbuf + (size_t)(l*4+3)*NB*ND, hbuf);
      k_gemm6<1><<<dim3((NTOK/128)*(3072/128)), 256, 0, stream>>>(
          hbuf, W1T + (size_t)l*ND*3072, b1 + (size_t)l*3072, nullptr, hidbuf, NTOK, 3072, ND);
      k_gemm6<2><<<dim3((NTOK/128)*(ND/128)), 256, 0, stream>>>(
          hidbuf, W2T + (size_t)l*3072*ND, b2 + (size_t)l*ND, xbuf, xbuf, NTOK, ND, 3072);
    }
    k_cln<<<NTOK/4, 256, 0, stream>>>(xbuf, gbuf + (size_t)32*NB*ND, gbuf + (size_t)33*NB*ND, hbuf);
    k_gemm6<0><<<dim3((NTOK/128)*(NV/128)), 256, 0, stream>>>(
        hbuf, WoutT, bout, nullptr, (float*)d_out, NTOK, NV, ND);
  } else {
    u16* hidbuf = region;
    for (int l = 0; l < NL; l++) {
      k_cln<<<NTOK/4, 256, 0, stream>>>(xbuf, gbuf + (size_t)(l*4+0)*NB*ND, gbuf + (size_t)(l*4+1)*NB*ND, hbuf);
      k_qkv<<<dim3(NTOK/64, NH), 256, 0, stream>>>(hbuf,
          Wq + (size_t)l*NH*NDH*NDH, Wk + (size_t)l*NH*NDH*NDH, Wv + (size_t)l*NH*NDH*NDH,
          qbuf, kbuf, vbuf);
      k_attn2<<<dim3(NB*NH, NS/64), 256, 0, stream>>>(qbuf, kbuf, vbuf, obuf);
      k_gemm<2><<<dim3(NTOK/64, ND/64), 256, 0, stream>>>(obuf, Wo + (size_t)l*ND*ND,
          bo + (size_t)l*ND, xbuf, xbuf, NTOK, ND, ND);
      k_cln<<<NTOK/4, 256, 0, stream>>>(xbuf, gbuf + (size_t)(l*4+2)*NB*ND, gbuf + (size_t)(l*4+3)*NB*ND, hbuf);
      for (int c = 0; c < 2; c++) {
        const size_t mo = (size_t)c * 4096;
        k_gemm<1><<<dim3(4096/64, 3072/64), 256, 0, stream>>>(hbuf + mo*ND, W1 + (size_t)l*ND*3072,
            b1 + (size_t)l*3072, nullptr, hidbuf, 4096, 3072, ND);
        k_gemm<2><<<dim3(4096/64, ND/64), 256, 0, stream>>>(hidbuf, W2 + (size_t)l*3072*ND,
            b2 + (size_t)l*ND, xbuf + mo*ND, xbuf + mo*ND, 4096, ND, 3072);
      }
    }
    k_cln<<<NTOK/4, 256, 0, stream>>>(xbuf, gbuf + (size_t)32*NB*ND, gbuf + (size_t)33*NB*ND, hbuf);
    k_gemm<0><<<dim3(NTOK/64, NV/64), 256, 0, stream>>>(hbuf, Wout, bout, nullptr, (float*)d_out, NTOK, NV, ND);
  }
}